// Round 1
// baseline (2203.931 us; speedup 1.0000x reference)
//
#include <hip/hip_runtime.h>
#include <hip/hip_bf16.h>
#include <math.h>

#define Bc 2
#define Sc 2048
#define Dc 1024
#define Hc 16
#define Ec 64
#define DFFc 4096
#define RAc 32
#define ROc 512
#define RFc 512
#define SCALEc 0.125f
#define LN_EPSc 1e-5f

// ---------------- LayerNorm: one block per row (D=1024, 256 thr x 4) ----------------
__global__ __launch_bounds__(256) void ln_kernel(const float* __restrict__ x,
                                                 const float* __restrict__ w,
                                                 const float* __restrict__ b,
                                                 float* __restrict__ out) {
  __shared__ float sm[8];
  int row = blockIdx.x;
  int tid = threadIdx.x;
  const float* xr = x + (size_t)row * Dc;
  float v[4];
  float sum = 0.f;
#pragma unroll
  for (int i = 0; i < 4; ++i) { v[i] = xr[tid + i * 256]; sum += v[i]; }
#pragma unroll
  for (int off = 32; off > 0; off >>= 1) sum += __shfl_down(sum, off, 64);
  if ((tid & 63) == 0) sm[tid >> 6] = sum;
  __syncthreads();
  float mean = (sm[0] + sm[1] + sm[2] + sm[3]) * (1.f / Dc);
  float var = 0.f;
#pragma unroll
  for (int i = 0; i < 4; ++i) { float d0 = v[i] - mean; var += d0 * d0; }
#pragma unroll
  for (int off = 32; off > 0; off >>= 1) var += __shfl_down(var, off, 64);
  if ((tid & 63) == 0) sm[4 + (tid >> 6)] = var;
  __syncthreads();
  float rstd = rsqrtf((sm[4] + sm[5] + sm[6] + sm[7]) * (1.f / Dc) + LN_EPSc);
  float* orow = out + (size_t)row * Dc;
#pragma unroll
  for (int i = 0; i < 4; ++i) {
    int c = tid + i * 256;
    orow[c] = (v[i] - mean) * rstd * w[c] + b[c];
  }
}

// ---------------- Generic NT GEMM: C[M,N] = A[M,K] * W[N,K]^T (+bias,+gelu,+res) ----
// 64x64 tile, BK=16, 256 threads, 4x4 per thread. M%64==0, N%64==0, K%16==0.
__global__ __launch_bounds__(256) void gemm_nt(const float* __restrict__ A,
                                               const float* __restrict__ W,
                                               float* __restrict__ C,
                                               const float* __restrict__ bias,
                                               const float* __restrict__ res,
                                               int M, int N, int K, int do_gelu) {
  __shared__ float As[16][68];
  __shared__ float Ws[16][68];
  int tid = threadIdx.x;
  int bn = blockIdx.x, bm = blockIdx.y;
  int tr = tid >> 4, tc = tid & 15;
  const float* Ab = A + (size_t)(bm * 64) * K;
  const float* Wb = W + (size_t)(bn * 64) * K;
  float acc[4][4] = {};
  int lr = tid >> 2;        // 0..63
  int lc = (tid & 3) * 4;   // 0,4,8,12
  for (int k0 = 0; k0 < K; k0 += 16) {
    float4 av = *(const float4*)(Ab + (size_t)lr * K + k0 + lc);
    float4 wv = *(const float4*)(Wb + (size_t)lr * K + k0 + lc);
    __syncthreads();
    As[lc + 0][lr] = av.x; As[lc + 1][lr] = av.y; As[lc + 2][lr] = av.z; As[lc + 3][lr] = av.w;
    Ws[lc + 0][lr] = wv.x; Ws[lc + 1][lr] = wv.y; Ws[lc + 2][lr] = wv.z; Ws[lc + 3][lr] = wv.w;
    __syncthreads();
#pragma unroll
    for (int kk = 0; kk < 16; ++kk) {
      float4 a4 = *(const float4*)(&As[kk][tr * 4]);
      float4 w4 = *(const float4*)(&Ws[kk][tc * 4]);
      float aa[4] = {a4.x, a4.y, a4.z, a4.w};
      float ww[4] = {w4.x, w4.y, w4.z, w4.w};
#pragma unroll
      for (int i = 0; i < 4; ++i)
#pragma unroll
        for (int j = 0; j < 4; ++j) acc[i][j] += aa[i] * ww[j];
    }
  }
#pragma unroll
  for (int i = 0; i < 4; ++i) {
    int m = bm * 64 + tr * 4 + i;
    int n0 = bn * 64 + tc * 4;
    float vv[4];
#pragma unroll
    for (int j = 0; j < 4; ++j) {
      vv[j] = acc[i][j];
      if (bias) vv[j] += bias[n0 + j];
      if (do_gelu) vv[j] = 0.5f * vv[j] * (1.f + erff(vv[j] * 0.70710678118f));
    }
    if (res) {
      float4 r4 = *(const float4*)(res + (size_t)m * N + n0);
      vv[0] += r4.x; vv[1] += r4.y; vv[2] += r4.z; vv[3] += r4.w;
    }
    float4 o4 = {vv[0], vv[1], vv[2], vv[3]};
    *(float4*)(C + (size_t)m * N + n0) = o4;
  }
}

// ---------------- Per-head rank expansion: q[b,h,s,e] = sum_r t[bs,h*32+r]*U[h,e,r]+bias
// grid = B*H*(S/32), block 256. t: [B*S, 512]; U: [H,64,32]; out: [B,H,S,64]
__global__ __launch_bounds__(256) void expand_head(const float* __restrict__ t,
                                                   const float* __restrict__ U,
                                                   const float* __restrict__ bias,
                                                   float* __restrict__ out) {
  __shared__ float Us[64][33];
  __shared__ float Ts[32][33];
  int blk = blockIdx.x;
  int sb = blk & 63;          // S/32 = 64
  int h = (blk >> 6) & 15;
  int b = blk >> 10;
  int tid = threadIdx.x;
  for (int i = tid; i < 64 * 32; i += 256) Us[i >> 5][i & 31] = U[h * 2048 + i];
  for (int i = tid; i < 32 * 32; i += 256) {
    int sr = i >> 5, r = i & 31;
    Ts[sr][r] = t[(size_t)(b * Sc + sb * 32 + sr) * 512 + h * 32 + r];
  }
  __syncthreads();
  int e = tid & 63;
  int sg = tid >> 6;
  float bv = bias[h * 64 + e];
#pragma unroll
  for (int si = 0; si < 8; ++si) {
    int sr = sg * 8 + si;
    float acc = bv;
#pragma unroll
    for (int r = 0; r < 32; ++r) acc += Ts[sr][r] * Us[e][r];
    out[((size_t)((b * Hc + h) * Sc) + sb * 32 + sr) * 64 + e] = acc;
  }
}

// ---------------- Causal flash attention, fp32. 1 thread = 1 q row. ----------------
// grid = B*H*(S/256), block 256. q,k,v: [B,H,S,64]; out: [B,S,D] (col = h*64+e)
__global__ __launch_bounds__(256) void attn_kernel(const float* __restrict__ q,
                                                   const float* __restrict__ k,
                                                   const float* __restrict__ v,
                                                   float* __restrict__ out) {
  __shared__ float Ks[32][64];
  __shared__ float Vs[32][64];
  int blk = blockIdx.x;
  int qb = blk & 7;            // S/256 = 8
  int h = (blk >> 3) & 15;
  int b = blk >> 7;
  const float* qbase = q + (size_t)(b * Hc + h) * Sc * Ec;
  const float* kbase = k + (size_t)(b * Hc + h) * Sc * Ec;
  const float* vbase = v + (size_t)(b * Hc + h) * Sc * Ec;
  int tid = threadIdx.x;
  int qi = qb * 256 + tid;
  float qr[64];
#pragma unroll
  for (int e4 = 0; e4 < 16; ++e4) {
    float4 t4 = *(const float4*)(qbase + (size_t)qi * Ec + e4 * 4);
    qr[e4 * 4 + 0] = t4.x * SCALEc; qr[e4 * 4 + 1] = t4.y * SCALEc;
    qr[e4 * 4 + 2] = t4.z * SCALEc; qr[e4 * 4 + 3] = t4.w * SCALEc;
  }
  float o[64];
#pragma unroll
  for (int e = 0; e < 64; ++e) o[e] = 0.f;
  float mcur = -1e30f, l = 0.f;
  int ntiles = qb * 8 + 8;
  for (int t = 0; t < ntiles; ++t) {
    __syncthreads();
    for (int i = tid; i < 512; i += 256) {
      ((float4*)Ks)[i] = ((const float4*)kbase)[t * 512 + i];
      ((float4*)Vs)[i] = ((const float4*)vbase)[t * 512 + i];
    }
    __syncthreads();
    float s[32];
#pragma unroll
    for (int j = 0; j < 32; ++j) {
      float d = 0.f;
      const float4* kp = (const float4*)(&Ks[j][0]);
#pragma unroll
      for (int e4 = 0; e4 < 16; ++e4) {
        float4 kk4 = kp[e4];
        d += qr[e4 * 4 + 0] * kk4.x + qr[e4 * 4 + 1] * kk4.y +
             qr[e4 * 4 + 2] * kk4.z + qr[e4 * 4 + 3] * kk4.w;
      }
      s[j] = (t * 32 + j <= qi) ? d : -1e30f;
    }
    float tmax = s[0];
#pragma unroll
    for (int j = 1; j < 32; ++j) tmax = fmaxf(tmax, s[j]);
    float mn = fmaxf(mcur, tmax);
    float corr = __expf(mcur - mn);
    mcur = mn;
    l *= corr;
#pragma unroll
    for (int e = 0; e < 64; ++e) o[e] *= corr;
#pragma unroll
    for (int j = 0; j < 32; ++j) {
      float p = __expf(s[j] - mcur);
      l += p;
      const float4* vp = (const float4*)(&Vs[j][0]);
#pragma unroll
      for (int e4 = 0; e4 < 16; ++e4) {
        float4 vv4 = vp[e4];
        o[e4 * 4 + 0] += p * vv4.x; o[e4 * 4 + 1] += p * vv4.y;
        o[e4 * 4 + 2] += p * vv4.z; o[e4 * 4 + 3] += p * vv4.w;
      }
    }
  }
  float inv = 1.f / l;
  float* orow = out + (size_t)(b * Sc + qi) * Dc + h * Ec;
#pragma unroll
  for (int e4 = 0; e4 < 16; ++e4) {
    float4 o4 = {o[e4 * 4] * inv, o[e4 * 4 + 1] * inv, o[e4 * 4 + 2] * inv, o[e4 * 4 + 3] * inv};
    *(float4*)(orow + e4 * 4) = o4;
  }
}

extern "C" void kernel_launch(void* const* d_in, const int* in_sizes, int n_in,
                              void* d_out, int out_size, void* d_ws, size_t ws_size,
                              hipStream_t stream) {
  const float* hidden = (const float*)d_in[0];
  const float* ln1_w = (const float*)d_in[1];
  const float* ln1_b = (const float*)d_in[2];
  const float* q_U = (const float*)d_in[3];
  const float* q_V = (const float*)d_in[4];
  const float* q_bias = (const float*)d_in[5];
  const float* k_U = (const float*)d_in[6];
  const float* k_V = (const float*)d_in[7];
  const float* k_bias = (const float*)d_in[8];
  const float* v_U = (const float*)d_in[9];
  const float* v_V = (const float*)d_in[10];
  const float* v_bias = (const float*)d_in[11];
  const float* out_U = (const float*)d_in[12];
  const float* out_V = (const float*)d_in[13];
  const float* out_bias = (const float*)d_in[14];
  const float* ln2_w = (const float*)d_in[15];
  const float* ln2_b = (const float*)d_in[16];
  const float* fc1_U = (const float*)d_in[17];
  const float* fc1_V = (const float*)d_in[18];
  const float* fc1_bias = (const float*)d_in[19];
  const float* fc2_U = (const float*)d_in[20];
  const float* fc2_V = (const float*)d_in[21];
  const float* fc2_bias = (const float*)d_in[22];
  float* out = (float*)d_out;
  float* ws = (float*)d_ws;

  // Arena layout (floats). Peak 23,068,672 floats = 92.3 MB.
  float* normed = ws;                 // [B*S, D]   4,194,304 (also reused as attn_out)
  float* qbuf = ws + 4194304;         // [B,H,S,E]  4,194,304
  float* kbuf = ws + 8388608;
  float* vbuf = ws + 12582912;
  float* rb = ws + 16777216;          // [B*S, 512] 2,097,152
  float* rb2 = ws + 4194304;          // FF phase (reuses qbuf)
  float* ffbuf = ws + 6291456;        // [B*S, 4096] 16,777,216

  const int M = Bc * Sc;  // 4096
  dim3 blk(256);

  // ---- LN1 ----
  ln_kernel<<<M, blk, 0, stream>>>(hidden, ln1_w, ln1_b, normed);

  // ---- QKV low-rank projections ----
  gemm_nt<<<dim3(8, 64), blk, 0, stream>>>(normed, q_V, rb, nullptr, nullptr, M, 512, Dc, 0);
  expand_head<<<2048, blk, 0, stream>>>(rb, q_U, q_bias, qbuf);
  gemm_nt<<<dim3(8, 64), blk, 0, stream>>>(normed, k_V, rb, nullptr, nullptr, M, 512, Dc, 0);
  expand_head<<<2048, blk, 0, stream>>>(rb, k_U, k_bias, kbuf);
  gemm_nt<<<dim3(8, 64), blk, 0, stream>>>(normed, v_V, rb, nullptr, nullptr, M, 512, Dc, 0);
  expand_head<<<2048, blk, 0, stream>>>(rb, v_U, v_bias, vbuf);

  // ---- causal attention (writes [B,S,D] into normed, which is now free) ----
  attn_kernel<<<256, blk, 0, stream>>>(qbuf, kbuf, vbuf, normed);

  // ---- output projection + residual ----
  gemm_nt<<<dim3(8, 64), blk, 0, stream>>>(normed, out_V, rb, nullptr, nullptr, M, ROc, Dc, 0);
  gemm_nt<<<dim3(16, 64), blk, 0, stream>>>(rb, out_U, out, out_bias, hidden, M, Dc, ROc, 0);

  // ---- LN2 + FF ----
  ln_kernel<<<M, blk, 0, stream>>>(out, ln2_w, ln2_b, normed);
  gemm_nt<<<dim3(8, 64), blk, 0, stream>>>(normed, fc1_V, rb2, nullptr, nullptr, M, RFc, Dc, 0);
  gemm_nt<<<dim3(64, 64), blk, 0, stream>>>(rb2, fc1_U, ffbuf, fc1_bias, nullptr, M, DFFc, RFc, 1);
  gemm_nt<<<dim3(8, 64), blk, 0, stream>>>(ffbuf, fc2_V, rb2, nullptr, nullptr, M, RFc, DFFc, 0);
  gemm_nt<<<dim3(16, 64), blk, 0, stream>>>(rb2, fc2_U, out, fc2_bias, out, M, Dc, RFc, 0);
}

// Round 2
// 1244.147 us; speedup vs baseline: 1.7714x; 1.7714x over previous
//
#include <hip/hip_runtime.h>
#include <hip/hip_bf16.h>
#include <math.h>

#define Bc 2
#define Sc 2048
#define Dc 1024
#define Hc 16
#define Ec 64
#define DFFc 4096
#define RAc 32
#define ROc 512
#define RFc 512
#define SCALEc 0.125f
#define LN_EPSc 1e-5f

typedef short bf16x8 __attribute__((ext_vector_type(8)));
typedef unsigned short u16x8 __attribute__((ext_vector_type(8)));
typedef float f32x4 __attribute__((ext_vector_type(4)));
#define MFMA16(a, b, c) __builtin_amdgcn_mfma_f32_16x16x32_bf16(a, b, c, 0, 0, 0)

static __device__ __forceinline__ unsigned short f2bf(float x) {
  unsigned u = __float_as_uint(x);
  unsigned r = (u + 0x7FFFu + ((u >> 16) & 1u)) >> 16;
  return (unsigned short)r;
}

// ---------------- LayerNorm: one block per row (D=1024, 256 thr x 4) ----------------
__global__ __launch_bounds__(256) void ln_kernel(const float* __restrict__ x,
                                                 const float* __restrict__ w,
                                                 const float* __restrict__ b,
                                                 float* __restrict__ out) {
  __shared__ float sm[8];
  int row = blockIdx.x;
  int tid = threadIdx.x;
  const float* xr = x + (size_t)row * Dc;
  float v[4];
  float sum = 0.f;
#pragma unroll
  for (int i = 0; i < 4; ++i) { v[i] = xr[tid + i * 256]; sum += v[i]; }
#pragma unroll
  for (int off = 32; off > 0; off >>= 1) sum += __shfl_down(sum, off, 64);
  if ((tid & 63) == 0) sm[tid >> 6] = sum;
  __syncthreads();
  float mean = (sm[0] + sm[1] + sm[2] + sm[3]) * (1.f / Dc);
  float var = 0.f;
#pragma unroll
  for (int i = 0; i < 4; ++i) { float d0 = v[i] - mean; var += d0 * d0; }
#pragma unroll
  for (int off = 32; off > 0; off >>= 1) var += __shfl_down(var, off, 64);
  if ((tid & 63) == 0) sm[4 + (tid >> 6)] = var;
  __syncthreads();
  float rstd = rsqrtf((sm[4] + sm[5] + sm[6] + sm[7]) * (1.f / Dc) + LN_EPSc);
  float* orow = out + (size_t)row * Dc;
#pragma unroll
  for (int i = 0; i < 4; ++i) {
    int c = tid + i * 256;
    orow[c] = (v[i] - mean) * rstd * w[c] + b[c];
  }
}

// ---------------- Generic NT GEMM: C[M,N] = A[M,K] * W[N,K]^T (+bias,+gelu,+res) ----
__global__ __launch_bounds__(256) void gemm_nt(const float* __restrict__ A,
                                               const float* __restrict__ W,
                                               float* __restrict__ C,
                                               const float* __restrict__ bias,
                                               const float* __restrict__ res,
                                               int M, int N, int K, int do_gelu) {
  __shared__ float As[16][68];
  __shared__ float Ws[16][68];
  int tid = threadIdx.x;
  int bn = blockIdx.x, bm = blockIdx.y;
  int tr = tid >> 4, tc = tid & 15;
  const float* Ab = A + (size_t)(bm * 64) * K;
  const float* Wb = W + (size_t)(bn * 64) * K;
  float acc[4][4] = {};
  int lr = tid >> 2;
  int lc = (tid & 3) * 4;
  for (int k0 = 0; k0 < K; k0 += 16) {
    float4 av = *(const float4*)(Ab + (size_t)lr * K + k0 + lc);
    float4 wv = *(const float4*)(Wb + (size_t)lr * K + k0 + lc);
    __syncthreads();
    As[lc + 0][lr] = av.x; As[lc + 1][lr] = av.y; As[lc + 2][lr] = av.z; As[lc + 3][lr] = av.w;
    Ws[lc + 0][lr] = wv.x; Ws[lc + 1][lr] = wv.y; Ws[lc + 2][lr] = wv.z; Ws[lc + 3][lr] = wv.w;
    __syncthreads();
#pragma unroll
    for (int kk = 0; kk < 16; ++kk) {
      float4 a4 = *(const float4*)(&As[kk][tr * 4]);
      float4 w4 = *(const float4*)(&Ws[kk][tc * 4]);
      float aa[4] = {a4.x, a4.y, a4.z, a4.w};
      float ww[4] = {w4.x, w4.y, w4.z, w4.w};
#pragma unroll
      for (int i = 0; i < 4; ++i)
#pragma unroll
        for (int j = 0; j < 4; ++j) acc[i][j] += aa[i] * ww[j];
    }
  }
#pragma unroll
  for (int i = 0; i < 4; ++i) {
    int m = bm * 64 + tr * 4 + i;
    int n0 = bn * 64 + tc * 4;
    float vv[4];
#pragma unroll
    for (int j = 0; j < 4; ++j) {
      vv[j] = acc[i][j];
      if (bias) vv[j] += bias[n0 + j];
      if (do_gelu) vv[j] = 0.5f * vv[j] * (1.f + erff(vv[j] * 0.70710678118f));
    }
    if (res) {
      float4 r4 = *(const float4*)(res + (size_t)m * N + n0);
      vv[0] += r4.x; vv[1] += r4.y; vv[2] += r4.z; vv[3] += r4.w;
    }
    float4 o4 = {vv[0], vv[1], vv[2], vv[3]};
    *(float4*)(C + (size_t)m * N + n0) = o4;
  }
}

// ---------------- Per-head rank expansion -> bf16 [B,H,S,64] (Q and K) --------------
__global__ __launch_bounds__(256) void expand_head_qk(const float* __restrict__ t,
                                                      const float* __restrict__ U,
                                                      const float* __restrict__ bias,
                                                      unsigned short* __restrict__ out) {
  __shared__ float Us[64][33];
  __shared__ float Ts[32][33];
  int blk = blockIdx.x;
  int sb = blk & 63;
  int h = (blk >> 6) & 15;
  int b = blk >> 10;
  int tid = threadIdx.x;
  for (int i = tid; i < 64 * 32; i += 256) Us[i >> 5][i & 31] = U[h * 2048 + i];
  for (int i = tid; i < 32 * 32; i += 256) {
    int sr = i >> 5, r = i & 31;
    Ts[sr][r] = t[(size_t)(b * Sc + sb * 32 + sr) * 512 + h * 32 + r];
  }
  __syncthreads();
  int e = tid & 63;
  int sg = tid >> 6;
  float bv = bias[h * 64 + e];
#pragma unroll
  for (int si = 0; si < 8; ++si) {
    int sr = sg * 8 + si;
    float acc = bv;
#pragma unroll
    for (int r = 0; r < 32; ++r) acc += Ts[sr][r] * Us[e][r];
    out[((size_t)((b * Hc + h) * Sc) + sb * 32 + sr) * 64 + e] = f2bf(acc);
  }
}

// ---------------- Per-head rank expansion -> bf16 TRANSPOSED [B,H,64,S] (V) ---------
__global__ __launch_bounds__(256) void expand_head_vT(const float* __restrict__ t,
                                                      const float* __restrict__ U,
                                                      const float* __restrict__ bias,
                                                      unsigned short* __restrict__ out) {
  __shared__ float Us[64][33];
  __shared__ float Ts[32][33];
  int blk = blockIdx.x;
  int sb = blk & 63;
  int h = (blk >> 6) & 15;
  int b = blk >> 10;
  int tid = threadIdx.x;
  for (int i = tid; i < 64 * 32; i += 256) Us[i >> 5][i & 31] = U[h * 2048 + i];
  for (int i = tid; i < 32 * 32; i += 256) {
    int sr = i >> 5, r = i & 31;
    Ts[sr][r] = t[(size_t)(b * Sc + sb * 32 + sr) * 512 + h * 32 + r];
  }
  __syncthreads();
  int e = tid & 63;
  int sg = tid >> 6;
  float bv = bias[h * 64 + e];
  u16x8 v8;
#pragma unroll
  for (int si = 0; si < 8; ++si) {
    int sr = sg * 8 + si;
    float acc = bv;
#pragma unroll
    for (int r = 0; r < 32; ++r) acc += Ts[sr][r] * Us[e][r];
    v8[si] = f2bf(acc);
  }
  // out row e, cols s = sb*32 + sg*8 .. +8 (contiguous)
  *(u16x8*)(out + ((size_t)((b * Hc + h) * Ec) + e) * Sc + sb * 32 + sg * 8) = v8;
}

// ---------------- Causal flash attention, bf16 MFMA. ----------------
// grid = B*H*(S/64), 4 waves/block, wave = 16 q-rows.
// q,k: [B,H,S,64] bf16; vt: [B,H,64,S] bf16; out: [B,S,D] fp32 (col = h*64+e)
__global__ __launch_bounds__(256) void attn_mfma(const unsigned short* __restrict__ q,
                                                 const unsigned short* __restrict__ k,
                                                 const unsigned short* __restrict__ vt,
                                                 float* __restrict__ out) {
  __shared__ unsigned short Pl[4][16][40];  // per-wave P tile, 80B row stride
  int tid = threadIdx.x;
  int wid = tid >> 6, lane = tid & 63;
  int blk = blockIdx.x;
  int qt = 31 - (blk & 31);  // heaviest tiles first
  int h = (blk >> 5) & 15;
  int b = blk >> 9;
  const unsigned short* qb = q + (size_t)(b * Hc + h) * Sc * Ec;
  const unsigned short* kb = k + (size_t)(b * Hc + h) * Sc * Ec;
  const unsigned short* vb = vt + (size_t)(b * Hc + h) * Ec * Sc;
  int q0 = qt * 64 + wid * 16;
  int cl = lane & 15;   // C col / A row
  int grp = lane >> 4;  // k-group
  // Q fragments (A): row = cl, k(e) = grp*8 + i (+32 for second k-step)
  bf16x8 aq0 = *(const bf16x8*)(qb + (size_t)(q0 + cl) * Ec + grp * 8);
  bf16x8 aq1 = *(const bf16x8*)(qb + (size_t)(q0 + cl) * Ec + 32 + grp * 8);
  f32x4 accO[4] = {};  // 4 e-tiles of O[16][64]
  float m[4] = {-1e30f, -1e30f, -1e30f, -1e30f};
  float lsum[4] = {};
  int ntiles = (q0 + 16 + 31) >> 5;
  for (int kt = 0; kt < ntiles; ++kt) {
    int kbase = kt * 32;
    f32x4 z = {0.f, 0.f, 0.f, 0.f};
    bf16x8 bk;
    bk = *(const bf16x8*)(kb + (size_t)(kbase + cl) * Ec + grp * 8);
    f32x4 c0 = MFMA16(aq0, bk, z);
    bk = *(const bf16x8*)(kb + (size_t)(kbase + cl) * Ec + 32 + grp * 8);
    c0 = MFMA16(aq1, bk, c0);
    bk = *(const bf16x8*)(kb + (size_t)(kbase + 16 + cl) * Ec + grp * 8);
    f32x4 c1 = MFMA16(aq0, bk, z);
    bk = *(const bf16x8*)(kb + (size_t)(kbase + 16 + cl) * Ec + 32 + grp * 8);
    c1 = MFMA16(aq1, bk, c1);
    bool last = (kt == ntiles - 1);
    float s0[4], s1[4];
#pragma unroll
    for (int r = 0; r < 4; ++r) {
      s0[r] = c0[r] * SCALEc;
      s1[r] = c1[r] * SCALEc;
      if (last) {
        int qrow = q0 + grp * 4 + r;
        if (kbase + cl > qrow) s0[r] = -1e30f;
        if (kbase + 16 + cl > qrow) s1[r] = -1e30f;
      }
    }
#pragma unroll
    for (int r = 0; r < 4; ++r) {
      float t = fmaxf(s0[r], s1[r]);
      t = fmaxf(t, __shfl_xor(t, 1, 64));
      t = fmaxf(t, __shfl_xor(t, 2, 64));
      t = fmaxf(t, __shfl_xor(t, 4, 64));
      t = fmaxf(t, __shfl_xor(t, 8, 64));
      float mn = fmaxf(m[r], t);
      float corr = __expf(m[r] - mn);
      m[r] = mn;
      float p0 = __expf(s0[r] - mn);
      float p1 = __expf(s1[r] - mn);
      Pl[wid][grp * 4 + r][cl] = f2bf(p0);
      Pl[wid][grp * 4 + r][16 + cl] = f2bf(p1);
      float ps = p0 + p1;
      ps += __shfl_xor(ps, 1, 64);
      ps += __shfl_xor(ps, 2, 64);
      ps += __shfl_xor(ps, 4, 64);
      ps += __shfl_xor(ps, 8, 64);
      lsum[r] = lsum[r] * corr + ps;
      accO[0][r] *= corr;
      accO[1][r] *= corr;
      accO[2][r] *= corr;
      accO[3][r] *= corr;
    }
    // P A-fragment: row = cl, k = grp*8 + i (within-wave LDS, no barrier needed)
    bf16x8 pa = *(const bf16x8*)(&Pl[wid][cl][grp * 8]);
#pragma unroll
    for (int et = 0; et < 4; ++et) {
      bf16x8 bv = *(const bf16x8*)(vb + (size_t)(et * 16 + cl) * Sc + kbase + grp * 8);
      accO[et] = MFMA16(pa, bv, accO[et]);
    }
  }
  float inv[4];
#pragma unroll
  for (int r = 0; r < 4; ++r) inv[r] = 1.f / lsum[r];
#pragma unroll
  for (int et = 0; et < 4; ++et)
#pragma unroll
    for (int r = 0; r < 4; ++r) {
      int qi = q0 + grp * 4 + r;
      out[((size_t)(b * Sc + qi)) * Dc + h * Ec + et * 16 + cl] = accO[et][r] * inv[r];
    }
}

extern "C" void kernel_launch(void* const* d_in, const int* in_sizes, int n_in,
                              void* d_out, int out_size, void* d_ws, size_t ws_size,
                              hipStream_t stream) {
  const float* hidden = (const float*)d_in[0];
  const float* ln1_w = (const float*)d_in[1];
  const float* ln1_b = (const float*)d_in[2];
  const float* q_U = (const float*)d_in[3];
  const float* q_V = (const float*)d_in[4];
  const float* q_bias = (const float*)d_in[5];
  const float* k_U = (const float*)d_in[6];
  const float* k_V = (const float*)d_in[7];
  const float* k_bias = (const float*)d_in[8];
  const float* v_U = (const float*)d_in[9];
  const float* v_V = (const float*)d_in[10];
  const float* v_bias = (const float*)d_in[11];
  const float* out_U = (const float*)d_in[12];
  const float* out_V = (const float*)d_in[13];
  const float* out_bias = (const float*)d_in[14];
  const float* ln2_w = (const float*)d_in[15];
  const float* ln2_b = (const float*)d_in[16];
  const float* fc1_U = (const float*)d_in[17];
  const float* fc1_V = (const float*)d_in[18];
  const float* fc1_bias = (const float*)d_in[19];
  const float* fc2_U = (const float*)d_in[20];
  const float* fc2_V = (const float*)d_in[21];
  const float* fc2_bias = (const float*)d_in[22];
  float* out = (float*)d_out;
  float* ws = (float*)d_ws;

  // Arena (floats):
  // [0,4M)    normed / attn_out
  // [4M,6M)   rb (rank buffer, also FF rank buffer)
  // [6M,8M)   qbuf  (bf16, 4M ushort)
  // [8M,10M)  kbuf  (bf16)
  // [10M,12M) vtbuf (bf16, transposed [B,H,64,S])
  // FF phase: [6M,22M) ffbuf (fp32) — reuses q/k/vt region
  float* normed = ws;
  float* rb = ws + 4194304;
  unsigned short* qbuf = (unsigned short*)(ws + 6291456);
  unsigned short* kbuf = (unsigned short*)(ws + 8388608);
  unsigned short* vtbuf = (unsigned short*)(ws + 10485760);
  float* ffbuf = ws + 6291456;

  const int M = Bc * Sc;  // 4096
  dim3 blk(256);

  // ---- LN1 ----
  ln_kernel<<<M, blk, 0, stream>>>(hidden, ln1_w, ln1_b, normed);

  // ---- QKV low-rank projections ----
  gemm_nt<<<dim3(8, 64), blk, 0, stream>>>(normed, q_V, rb, nullptr, nullptr, M, 512, Dc, 0);
  expand_head_qk<<<2048, blk, 0, stream>>>(rb, q_U, q_bias, qbuf);
  gemm_nt<<<dim3(8, 64), blk, 0, stream>>>(normed, k_V, rb, nullptr, nullptr, M, 512, Dc, 0);
  expand_head_qk<<<2048, blk, 0, stream>>>(rb, k_U, k_bias, kbuf);
  gemm_nt<<<dim3(8, 64), blk, 0, stream>>>(normed, v_V, rb, nullptr, nullptr, M, 512, Dc, 0);
  expand_head_vT<<<2048, blk, 0, stream>>>(rb, v_U, v_bias, vtbuf);

  // ---- causal attention (bf16 MFMA) -> normed ----
  attn_mfma<<<1024, blk, 0, stream>>>(qbuf, kbuf, vtbuf, normed);

  // ---- output projection + residual ----
  gemm_nt<<<dim3(8, 64), blk, 0, stream>>>(normed, out_V, rb, nullptr, nullptr, M, ROc, Dc, 0);
  gemm_nt<<<dim3(16, 64), blk, 0, stream>>>(rb, out_U, out, out_bias, hidden, M, Dc, ROc, 0);

  // ---- LN2 + FF ----
  ln_kernel<<<M, blk, 0, stream>>>(out, ln2_w, ln2_b, normed);
  gemm_nt<<<dim3(8, 64), blk, 0, stream>>>(normed, fc1_V, rb, nullptr, nullptr, M, RFc, Dc, 0);
  gemm_nt<<<dim3(64, 64), blk, 0, stream>>>(rb, fc1_U, ffbuf, fc1_bias, nullptr, M, DFFc, RFc, 1);
  gemm_nt<<<dim3(8, 64), blk, 0, stream>>>(ffbuf, fc2_V, rb, nullptr, nullptr, M, RFc, DFFc, 0);
  gemm_nt<<<dim3(16, 64), blk, 0, stream>>>(rb, fc2_U, out, fc2_bias, out, M, Dc, RFc, 0);
}

// Round 3
// 509.507 us; speedup vs baseline: 4.3256x; 2.4419x over previous
//
#include <hip/hip_runtime.h>
#include <hip/hip_bf16.h>
#include <math.h>

#define Bc 2
#define Sc 2048
#define Dc 1024
#define Hc 16
#define Ec 64
#define DFFc 4096
#define SCALEc 0.125f
#define LN_EPSc 1e-5f

typedef short bf16x8 __attribute__((ext_vector_type(8)));
typedef unsigned short u16x4 __attribute__((ext_vector_type(4)));
typedef unsigned short u16x8 __attribute__((ext_vector_type(8)));
typedef float f32x4 __attribute__((ext_vector_type(4)));
#define MFMA16(a, b, c) __builtin_amdgcn_mfma_f32_16x16x32_bf16(a, b, c, 0, 0, 0)
#define GLDS16(g, l)                                                            \
  __builtin_amdgcn_global_load_lds((const __attribute__((address_space(1))) void*)(g), \
                                   (__attribute__((address_space(3))) void*)(l), 16, 0, 0)

static __device__ __forceinline__ unsigned short f2bf(float x) {
  unsigned u = __float_as_uint(x);
  unsigned r = (u + 0x7FFFu + ((u >> 16) & 1u)) >> 16;
  return (unsigned short)r;
}

// ---------------- fp32 -> bf16 weight conversion, 3 tensors per launch -------------
__global__ __launch_bounds__(256) void convert3(const float* __restrict__ a, int na,
                                                const float* __restrict__ b, int nb,
                                                const float* __restrict__ c, int nc,
                                                unsigned short* __restrict__ oa,
                                                unsigned short* __restrict__ ob,
                                                unsigned short* __restrict__ oc) {
  int i = (blockIdx.x * 256 + threadIdx.x) * 4;
  const float* s;
  unsigned short* d;
  int off;
  if (i < na) { s = a; d = oa; off = i; }
  else if (i < na + nb) { s = b; d = ob; off = i - na; }
  else if (i < na + nb + nc) { s = c; d = oc; off = i - na - nb; }
  else return;
  float4 v = *(const float4*)(s + off);
  u16x4 o = {f2bf(v.x), f2bf(v.y), f2bf(v.z), f2bf(v.w)};
  *(u16x4*)(d + off) = o;
}

// ---------------- LayerNorm -> bf16 out ----------------
__global__ __launch_bounds__(256) void ln_bf16(const float* __restrict__ x,
                                               const float* __restrict__ w,
                                               const float* __restrict__ b,
                                               unsigned short* __restrict__ out) {
  __shared__ float sm[8];
  int row = blockIdx.x;
  int tid = threadIdx.x;
  const float* xr = x + (size_t)row * Dc;
  float v[4];
  float sum = 0.f;
#pragma unroll
  for (int i = 0; i < 4; ++i) { v[i] = xr[tid + i * 256]; sum += v[i]; }
#pragma unroll
  for (int off = 32; off > 0; off >>= 1) sum += __shfl_down(sum, off, 64);
  if ((tid & 63) == 0) sm[tid >> 6] = sum;
  __syncthreads();
  float mean = (sm[0] + sm[1] + sm[2] + sm[3]) * (1.f / Dc);
  float var = 0.f;
#pragma unroll
  for (int i = 0; i < 4; ++i) { float d0 = v[i] - mean; var += d0 * d0; }
#pragma unroll
  for (int off = 32; off > 0; off >>= 1) var += __shfl_down(var, off, 64);
  if ((tid & 63) == 0) sm[4 + (tid >> 6)] = var;
  __syncthreads();
  float rstd = rsqrtf((sm[4] + sm[5] + sm[6] + sm[7]) * (1.f / Dc) + LN_EPSc);
  unsigned short* orow = out + (size_t)row * Dc;
#pragma unroll
  for (int i = 0; i < 4; ++i) {
    int c = tid + i * 256;
    orow[c] = f2bf((v[i] - mean) * rstd * w[c] + b[c]);
  }
}

// ---------------- bf16 MFMA NT GEMM: C[M,N] = A[M,K] * W[N,K]^T -------------------
// BMxBN tile, BK=32, 256 threads (4 waves, 2x2). m97-style 2-barrier K-loop,
// global_load_lds width 16, linear LDS.
template <int BM, int BN>
__global__ __launch_bounds__(256) void gemm_bf16(const unsigned short* __restrict__ A,
                                                 const unsigned short* __restrict__ W,
                                                 float* __restrict__ Cf,
                                                 unsigned short* __restrict__ Cb,
                                                 const float* __restrict__ bias,
                                                 const float* __restrict__ res,
                                                 int M, int N, int K, int gelu) {
  constexpr int MT = BM / 32;
  constexpr int NT = BN / 32;
  __shared__ unsigned short As[BM * 32];
  __shared__ unsigned short Bs[BN * 32];
  int tid = threadIdx.x;
  int lane = tid & 63;
  int wid = tid >> 6;
  int cl = lane & 15, grp = lane >> 4;
  int wr = wid >> 1, wc = wid & 1;
  const unsigned short* Ab = A + (size_t)(blockIdx.y * BM) * K;
  const unsigned short* Wb = W + (size_t)(blockIdx.x * BN) * K;
  f32x4 acc[MT][NT];
  f32x4 z4 = {0.f, 0.f, 0.f, 0.f};
#pragma unroll
  for (int i = 0; i < MT; ++i)
#pragma unroll
    for (int j = 0; j < NT; ++j) acc[i][j] = z4;
  int r0 = tid >> 2;
  int g0 = (tid & 3) * 8;
  for (int k0 = 0; k0 < K; k0 += 32) {
    __syncthreads();
#pragma unroll
    for (int l = 0; l < BM / 64; ++l)
      GLDS16(Ab + (size_t)(r0 + l * 64) * K + k0 + g0, &As[(tid + l * 256) * 8]);
#pragma unroll
    for (int l = 0; l < BN / 64; ++l)
      GLDS16(Wb + (size_t)(r0 + l * 64) * K + k0 + g0, &Bs[(tid + l * 256) * 8]);
    __syncthreads();
    bf16x8 af[MT], bfr[NT];
#pragma unroll
    for (int i = 0; i < MT; ++i)
      af[i] = *(const bf16x8*)&As[(wr * (BM / 2) + i * 16 + cl) * 32 + grp * 8];
#pragma unroll
    for (int j = 0; j < NT; ++j)
      bfr[j] = *(const bf16x8*)&Bs[(wc * (BN / 2) + j * 16 + cl) * 32 + grp * 8];
#pragma unroll
    for (int i = 0; i < MT; ++i)
#pragma unroll
      for (int j = 0; j < NT; ++j) acc[i][j] = MFMA16(af[i], bfr[j], acc[i][j]);
  }
#pragma unroll
  for (int i = 0; i < MT; ++i) {
    int row = blockIdx.y * BM + wr * (BM / 2) + i * 16 + grp * 4;
#pragma unroll
    for (int j = 0; j < NT; ++j) {
      int col = blockIdx.x * BN + wc * (BN / 2) + j * 16 + cl;
      float bv = bias ? bias[col] : 0.f;
#pragma unroll
      for (int r = 0; r < 4; ++r) {
        float v = acc[i][j][r] + bv;
        if (gelu) v = 0.5f * v * (1.f + erff(v * 0.70710678118f));
        if (res) v += res[(size_t)(row + r) * N + col];
        if (Cb) Cb[(size_t)(row + r) * N + col] = f2bf(v);
        else Cf[(size_t)(row + r) * N + col] = v;
      }
    }
  }
}

// ---------------- Per-head rank expansion -> bf16 [B,H,S,64] (Q and K) --------------
__global__ __launch_bounds__(256) void expand_head_qk(const float* __restrict__ t, int tstride,
                                                      const float* __restrict__ U,
                                                      const float* __restrict__ bias,
                                                      unsigned short* __restrict__ out) {
  __shared__ float Us[64][33];
  __shared__ float Ts[32][33];
  int blk = blockIdx.x;
  int sb = blk & 63;
  int h = (blk >> 6) & 15;
  int b = blk >> 10;
  int tid = threadIdx.x;
  for (int i = tid; i < 64 * 32; i += 256) Us[i >> 5][i & 31] = U[h * 2048 + i];
  for (int i = tid; i < 32 * 32; i += 256) {
    int sr = i >> 5, r = i & 31;
    Ts[sr][r] = t[(size_t)(b * Sc + sb * 32 + sr) * tstride + h * 32 + r];
  }
  __syncthreads();
  int e = tid & 63;
  int sg = tid >> 6;
  float bv = bias[h * 64 + e];
#pragma unroll
  for (int si = 0; si < 8; ++si) {
    int sr = sg * 8 + si;
    float acc = bv;
#pragma unroll
    for (int r = 0; r < 32; ++r) acc += Ts[sr][r] * Us[e][r];
    out[((size_t)((b * Hc + h) * Sc) + sb * 32 + sr) * 64 + e] = f2bf(acc);
  }
}

// ---------------- Per-head rank expansion -> bf16 TRANSPOSED [B,H,64,S] (V) ---------
__global__ __launch_bounds__(256) void expand_head_vT(const float* __restrict__ t, int tstride,
                                                      const float* __restrict__ U,
                                                      const float* __restrict__ bias,
                                                      unsigned short* __restrict__ out) {
  __shared__ float Us[64][33];
  __shared__ float Ts[32][33];
  int blk = blockIdx.x;
  int sb = blk & 63;
  int h = (blk >> 6) & 15;
  int b = blk >> 10;
  int tid = threadIdx.x;
  for (int i = tid; i < 64 * 32; i += 256) Us[i >> 5][i & 31] = U[h * 2048 + i];
  for (int i = tid; i < 32 * 32; i += 256) {
    int sr = i >> 5, r = i & 31;
    Ts[sr][r] = t[(size_t)(b * Sc + sb * 32 + sr) * tstride + h * 32 + r];
  }
  __syncthreads();
  int e = tid & 63;
  int sg = tid >> 6;
  float bv = bias[h * 64 + e];
  u16x8 v8;
#pragma unroll
  for (int si = 0; si < 8; ++si) {
    int sr = sg * 8 + si;
    float acc = bv;
#pragma unroll
    for (int r = 0; r < 32; ++r) acc += Ts[sr][r] * Us[e][r];
    v8[si] = f2bf(acc);
  }
  *(u16x8*)(out + ((size_t)((b * Hc + h) * Ec) + e) * Sc + sb * 32 + sg * 8) = v8;
}

// ---------------- Causal flash attention, bf16 MFMA, bf16 out ----------------
__global__ __launch_bounds__(256) void attn_mfma(const unsigned short* __restrict__ q,
                                                 const unsigned short* __restrict__ k,
                                                 const unsigned short* __restrict__ vt,
                                                 unsigned short* __restrict__ out) {
  __shared__ unsigned short Pl[4][16][40];
  int tid = threadIdx.x;
  int wid = tid >> 6, lane = tid & 63;
  int blk = blockIdx.x;
  int qt = 31 - (blk & 31);
  int h = (blk >> 5) & 15;
  int b = blk >> 9;
  const unsigned short* qb = q + (size_t)(b * Hc + h) * Sc * Ec;
  const unsigned short* kb = k + (size_t)(b * Hc + h) * Sc * Ec;
  const unsigned short* vb = vt + (size_t)(b * Hc + h) * Ec * Sc;
  int q0 = qt * 64 + wid * 16;
  int cl = lane & 15;
  int grp = lane >> 4;
  bf16x8 aq0 = *(const bf16x8*)(qb + (size_t)(q0 + cl) * Ec + grp * 8);
  bf16x8 aq1 = *(const bf16x8*)(qb + (size_t)(q0 + cl) * Ec + 32 + grp * 8);
  f32x4 accO[4] = {};
  float m[4] = {-1e30f, -1e30f, -1e30f, -1e30f};
  float lsum[4] = {};
  int ntiles = (q0 + 16 + 31) >> 5;
  for (int kt = 0; kt < ntiles; ++kt) {
    int kbase = kt * 32;
    f32x4 z = {0.f, 0.f, 0.f, 0.f};
    bf16x8 bk;
    bk = *(const bf16x8*)(kb + (size_t)(kbase + cl) * Ec + grp * 8);
    f32x4 c0 = MFMA16(aq0, bk, z);
    bk = *(const bf16x8*)(kb + (size_t)(kbase + cl) * Ec + 32 + grp * 8);
    c0 = MFMA16(aq1, bk, c0);
    bk = *(const bf16x8*)(kb + (size_t)(kbase + 16 + cl) * Ec + grp * 8);
    f32x4 c1 = MFMA16(aq0, bk, z);
    bk = *(const bf16x8*)(kb + (size_t)(kbase + 16 + cl) * Ec + 32 + grp * 8);
    c1 = MFMA16(aq1, bk, c1);
    bool last = (kt == ntiles - 1);
    float s0[4], s1[4];
#pragma unroll
    for (int r = 0; r < 4; ++r) {
      s0[r] = c0[r] * SCALEc;
      s1[r] = c1[r] * SCALEc;
      if (last) {
        int qrow = q0 + grp * 4 + r;
        if (kbase + cl > qrow) s0[r] = -1e30f;
        if (kbase + 16 + cl > qrow) s1[r] = -1e30f;
      }
    }
#pragma unroll
    for (int r = 0; r < 4; ++r) {
      float t = fmaxf(s0[r], s1[r]);
      t = fmaxf(t, __shfl_xor(t, 1, 64));
      t = fmaxf(t, __shfl_xor(t, 2, 64));
      t = fmaxf(t, __shfl_xor(t, 4, 64));
      t = fmaxf(t, __shfl_xor(t, 8, 64));
      float mn = fmaxf(m[r], t);
      float corr = __expf(m[r] - mn);
      m[r] = mn;
      float p0 = __expf(s0[r] - mn);
      float p1 = __expf(s1[r] - mn);
      Pl[wid][grp * 4 + r][cl] = f2bf(p0);
      Pl[wid][grp * 4 + r][16 + cl] = f2bf(p1);
      float ps = p0 + p1;
      ps += __shfl_xor(ps, 1, 64);
      ps += __shfl_xor(ps, 2, 64);
      ps += __shfl_xor(ps, 4, 64);
      ps += __shfl_xor(ps, 8, 64);
      lsum[r] = lsum[r] * corr + ps;
      accO[0][r] *= corr;
      accO[1][r] *= corr;
      accO[2][r] *= corr;
      accO[3][r] *= corr;
    }
    bf16x8 pa = *(const bf16x8*)(&Pl[wid][cl][grp * 8]);
#pragma unroll
    for (int et = 0; et < 4; ++et) {
      bf16x8 bv = *(const bf16x8*)(vb + (size_t)(et * 16 + cl) * Sc + kbase + grp * 8);
      accO[et] = MFMA16(pa, bv, accO[et]);
    }
  }
  float inv[4];
#pragma unroll
  for (int r = 0; r < 4; ++r) inv[r] = 1.f / lsum[r];
#pragma unroll
  for (int et = 0; et < 4; ++et)
#pragma unroll
    for (int r = 0; r < 4; ++r) {
      int qi = q0 + grp * 4 + r;
      out[((size_t)(b * Sc + qi)) * Dc + h * Ec + et * 16 + cl] = f2bf(accO[et][r] * inv[r]);
    }
}

extern "C" void kernel_launch(void* const* d_in, const int* in_sizes, int n_in,
                              void* d_out, int out_size, void* d_ws, size_t ws_size,
                              hipStream_t stream) {
  const float* hidden = (const float*)d_in[0];
  const float* ln1_w = (const float*)d_in[1];
  const float* ln1_b = (const float*)d_in[2];
  const float* q_U = (const float*)d_in[3];
  const float* q_V = (const float*)d_in[4];
  const float* q_bias = (const float*)d_in[5];
  const float* k_U = (const float*)d_in[6];
  const float* k_V = (const float*)d_in[7];
  const float* k_bias = (const float*)d_in[8];
  const float* v_U = (const float*)d_in[9];
  const float* v_V = (const float*)d_in[10];
  const float* v_bias = (const float*)d_in[11];
  const float* out_U = (const float*)d_in[12];
  const float* out_V = (const float*)d_in[13];
  const float* out_bias = (const float*)d_in[14];
  const float* ln2_w = (const float*)d_in[15];
  const float* ln2_b = (const float*)d_in[16];
  const float* fc1_U = (const float*)d_in[17];
  const float* fc1_V = (const float*)d_in[18];
  const float* fc1_bias = (const float*)d_in[19];
  const float* fc2_U = (const float*)d_in[20];
  const float* fc2_V = (const float*)d_in[21];
  const float* fc2_bias = (const float*)d_in[22];
  float* out = (float*)d_out;
  float* ws = (float*)d_ws;
  unsigned short* wsu = (unsigned short*)d_ws;

  // ---- bf16 weight arena (ushort offsets) ----
  unsigned short* wQKV = wsu;               // [1536,1024] (q_V|k_V|v_V)
  unsigned short* wKV = wsu + 524288;
  unsigned short* wVV = wsu + 1048576;
  unsigned short* wOUTV = wsu + 1572864;    // [512,1024]
  unsigned short* wOUTU = wsu + 2097152;    // [1024,512]
  unsigned short* wFC1V = wsu + 2621440;    // [512,1024]
  unsigned short* wFC1U = wsu + 3145728;    // [4096,512]
  unsigned short* wFC2V = wsu + 5242880;    // [512,4096]
  unsigned short* wFC2U = wsu + 7340032;    // [1024,512]

  // ---- activation arena (float offsets) ----
  float* h1 = ws + 4194304;                          // [4096,1024] fp32
  unsigned short* attn_out = (unsigned short*)(ws + 6291456);  // [4096,1024] bf16
  unsigned short* normed = (unsigned short*)(ws + 8388608);    // [4096,1024] bf16
  float* rb = ws + 10485760;                         // [4096,1536] fp32 (QKV t)
  unsigned short* rbB = (unsigned short*)(ws + 10485760);      // [4096,512] bf16
  unsigned short* ff = (unsigned short*)(ws + 11534336);       // [4096,4096] bf16
  unsigned short* qbuf = (unsigned short*)(ws + 16777216);
  unsigned short* kbuf = (unsigned short*)(ws + 18874368);
  unsigned short* rbG = (unsigned short*)(ws + 19922944);      // [4096,512] bf16
  unsigned short* vtbuf = (unsigned short*)(ws + 20971520);

  const int M = Bc * Sc;  // 4096
  dim3 blk(256);

  // ---- weight conversion ----
  convert3<<<1536, blk, 0, stream>>>(q_V, 524288, k_V, 524288, v_V, 524288, wQKV, wKV, wVV);
  convert3<<<1536, blk, 0, stream>>>(out_V, 524288, out_U, 524288, fc1_V, 524288, wOUTV, wOUTU, wFC1V);
  convert3<<<4608, blk, 0, stream>>>(fc1_U, 2097152, fc2_V, 2097152, fc2_U, 524288, wFC1U, wFC2V, wFC2U);

  // ---- LN1 ----
  ln_bf16<<<M, blk, 0, stream>>>(hidden, ln1_w, ln1_b, normed);

  // ---- fused QKV rank contraction: rb[4096,1536] = normed * [qV|kV|vV]^T ----
  gemm_bf16<64, 64><<<dim3(24, 64), blk, 0, stream>>>(normed, wQKV, rb, nullptr, nullptr, nullptr,
                                                      M, 1536, Dc, 0);
  expand_head_qk<<<2048, blk, 0, stream>>>(rb, 1536, q_U, q_bias, qbuf);
  expand_head_qk<<<2048, blk, 0, stream>>>(rb + 512, 1536, k_U, k_bias, kbuf);
  expand_head_vT<<<2048, blk, 0, stream>>>(rb + 1024, 1536, v_U, v_bias, vtbuf);

  // ---- causal attention -> attn_out (bf16) ----
  attn_mfma<<<1024, blk, 0, stream>>>(qbuf, kbuf, vtbuf, attn_out);

  // ---- output projection + residual -> h1 (fp32) ----
  gemm_bf16<64, 64><<<dim3(8, 64), blk, 0, stream>>>(attn_out, wOUTV, nullptr, rbB, nullptr, nullptr,
                                                     M, 512, Dc, 0);
  gemm_bf16<64, 64><<<dim3(16, 64), blk, 0, stream>>>(rbB, wOUTU, h1, nullptr, out_bias, hidden,
                                                      M, Dc, 512, 0);

  // ---- LN2 + FF ----
  ln_bf16<<<M, blk, 0, stream>>>(h1, ln2_w, ln2_b, normed);
  gemm_bf16<64, 64><<<dim3(8, 64), blk, 0, stream>>>(normed, wFC1V, nullptr, rbB, nullptr, nullptr,
                                                     M, 512, Dc, 0);
  gemm_bf16<128, 128><<<dim3(32, 32), blk, 0, stream>>>(rbB, wFC1U, nullptr, ff, fc1_bias, nullptr,
                                                        M, DFFc, 512, 1);
  gemm_bf16<64, 64><<<dim3(8, 64), blk, 0, stream>>>(ff, wFC2V, nullptr, rbG, nullptr, nullptr,
                                                     M, 512, DFFc, 0);
  gemm_bf16<64, 64><<<dim3(16, 64), blk, 0, stream>>>(rbG, wFC2U, out, nullptr, fc2_bias, h1,
                                                      M, Dc, 512, 0);
}

// Round 4
// 358.108 us; speedup vs baseline: 6.1544x; 1.4228x over previous
//
#include <hip/hip_runtime.h>
#include <hip/hip_bf16.h>
#include <math.h>

#define Bc 2
#define Sc 2048
#define Dc 1024
#define Hc 16
#define Ec 64
#define DFFc 4096
#define SCALEc 0.125f
#define SCLOG2E 0.18033688f  /* SCALE * log2(e) */
#define LN_EPSc 1e-5f

typedef short bf16x8 __attribute__((ext_vector_type(8)));
typedef unsigned short u16x4 __attribute__((ext_vector_type(4)));
typedef unsigned short u16x8 __attribute__((ext_vector_type(8)));
typedef float f32x4 __attribute__((ext_vector_type(4)));
typedef float f32x16 __attribute__((ext_vector_type(16)));
typedef unsigned int u32x4 __attribute__((ext_vector_type(4)));
#define MFMA16(a, b, c) __builtin_amdgcn_mfma_f32_16x16x32_bf16(a, b, c, 0, 0, 0)
#define MFMA32(a, b, c) __builtin_amdgcn_mfma_f32_32x32x16_bf16(a, b, c, 0, 0, 0)
#define GLDS16(g, l)                                                            \
  __builtin_amdgcn_global_load_lds((const __attribute__((address_space(1))) void*)(g), \
                                   (__attribute__((address_space(3))) void*)(l), 16, 0, 0)

static __device__ __forceinline__ unsigned short f2bf(float x) {
  unsigned u = __float_as_uint(x);
  unsigned r = (u + 0x7FFFu + ((u >> 16) & 1u)) >> 16;
  return (unsigned short)r;
}
static __device__ __forceinline__ unsigned cvtpk(float lo, float hi) {
  unsigned r;
  asm("v_cvt_pk_bf16_f32 %0, %1, %2" : "=v"(r) : "v"(lo), "v"(hi));
  return r;
}

// ---------------- fp32 -> bf16 weight conversion, 3 tensors per launch -------------
__global__ __launch_bounds__(256) void convert3(const float* __restrict__ a, int na,
                                                const float* __restrict__ b, int nb,
                                                const float* __restrict__ c, int nc,
                                                unsigned short* __restrict__ oa,
                                                unsigned short* __restrict__ ob,
                                                unsigned short* __restrict__ oc) {
  int i = (blockIdx.x * 256 + threadIdx.x) * 4;
  const float* s;
  unsigned short* d;
  int off;
  if (i < na) { s = a; d = oa; off = i; }
  else if (i < na + nb) { s = b; d = ob; off = i - na; }
  else if (i < na + nb + nc) { s = c; d = oc; off = i - na - nb; }
  else return;
  float4 v = *(const float4*)(s + off);
  u16x4 o = {f2bf(v.x), f2bf(v.y), f2bf(v.z), f2bf(v.w)};
  *(u16x4*)(d + off) = o;
}

// ---------------- LayerNorm -> bf16 out ----------------
__global__ __launch_bounds__(256) void ln_bf16(const float* __restrict__ x,
                                               const float* __restrict__ w,
                                               const float* __restrict__ b,
                                               unsigned short* __restrict__ out) {
  __shared__ float sm[8];
  int row = blockIdx.x;
  int tid = threadIdx.x;
  const float* xr = x + (size_t)row * Dc;
  float v[4];
  float sum = 0.f;
#pragma unroll
  for (int i = 0; i < 4; ++i) { v[i] = xr[tid + i * 256]; sum += v[i]; }
#pragma unroll
  for (int off = 32; off > 0; off >>= 1) sum += __shfl_down(sum, off, 64);
  if ((tid & 63) == 0) sm[tid >> 6] = sum;
  __syncthreads();
  float mean = (sm[0] + sm[1] + sm[2] + sm[3]) * (1.f / Dc);
  float var = 0.f;
#pragma unroll
  for (int i = 0; i < 4; ++i) { float d0 = v[i] - mean; var += d0 * d0; }
#pragma unroll
  for (int off = 32; off > 0; off >>= 1) var += __shfl_down(var, off, 64);
  if ((tid & 63) == 0) sm[4 + (tid >> 6)] = var;
  __syncthreads();
  float rstd = rsqrtf((sm[4] + sm[5] + sm[6] + sm[7]) * (1.f / Dc) + LN_EPSc);
  unsigned short* orow = out + (size_t)row * Dc;
#pragma unroll
  for (int i = 0; i < 4; ++i) {
    int c = tid + i * 256;
    orow[c] = f2bf((v[i] - mean) * rstd * w[c] + b[c]);
  }
}

// ---------------- bf16 MFMA NT GEMM: C[M,N] = A[M,K] * W[N,K]^T -------------------
template <int BM, int BN>
__global__ __launch_bounds__(256) void gemm_bf16(const unsigned short* __restrict__ A,
                                                 const unsigned short* __restrict__ W,
                                                 float* __restrict__ Cf,
                                                 unsigned short* __restrict__ Cb,
                                                 const float* __restrict__ bias,
                                                 const float* __restrict__ res,
                                                 int M, int N, int K, int gelu) {
  constexpr int MT = BM / 32;
  constexpr int NT = BN / 32;
  __shared__ unsigned short As[BM * 32];
  __shared__ unsigned short Bs[BN * 32];
  int tid = threadIdx.x;
  int lane = tid & 63;
  int wid = tid >> 6;
  int cl = lane & 15, grp = lane >> 4;
  int wr = wid >> 1, wc = wid & 1;
  const unsigned short* Ab = A + (size_t)(blockIdx.y * BM) * K;
  const unsigned short* Wb = W + (size_t)(blockIdx.x * BN) * K;
  f32x4 acc[MT][NT];
  f32x4 z4 = {0.f, 0.f, 0.f, 0.f};
#pragma unroll
  for (int i = 0; i < MT; ++i)
#pragma unroll
    for (int j = 0; j < NT; ++j) acc[i][j] = z4;
  int r0 = tid >> 2;
  int g0 = (tid & 3) * 8;
  for (int k0 = 0; k0 < K; k0 += 32) {
    __syncthreads();
#pragma unroll
    for (int l = 0; l < BM / 64; ++l)
      GLDS16(Ab + (size_t)(r0 + l * 64) * K + k0 + g0, &As[(tid + l * 256) * 8]);
#pragma unroll
    for (int l = 0; l < BN / 64; ++l)
      GLDS16(Wb + (size_t)(r0 + l * 64) * K + k0 + g0, &Bs[(tid + l * 256) * 8]);
    __syncthreads();
    bf16x8 af[MT], bfr[NT];
#pragma unroll
    for (int i = 0; i < MT; ++i)
      af[i] = *(const bf16x8*)&As[(wr * (BM / 2) + i * 16 + cl) * 32 + grp * 8];
#pragma unroll
    for (int j = 0; j < NT; ++j)
      bfr[j] = *(const bf16x8*)&Bs[(wc * (BN / 2) + j * 16 + cl) * 32 + grp * 8];
#pragma unroll
    for (int i = 0; i < MT; ++i)
#pragma unroll
      for (int j = 0; j < NT; ++j) acc[i][j] = MFMA16(af[i], bfr[j], acc[i][j]);
  }
#pragma unroll
  for (int i = 0; i < MT; ++i) {
    int row = blockIdx.y * BM + wr * (BM / 2) + i * 16 + grp * 4;
#pragma unroll
    for (int j = 0; j < NT; ++j) {
      int col = blockIdx.x * BN + wc * (BN / 2) + j * 16 + cl;
      float bv = bias ? bias[col] : 0.f;
#pragma unroll
      for (int r = 0; r < 4; ++r) {
        float v = acc[i][j][r] + bv;
        if (gelu) v = 0.5f * v * (1.f + erff(v * 0.70710678118f));
        if (res) v += res[(size_t)(row + r) * N + col];
        if (Cb) Cb[(size_t)(row + r) * N + col] = f2bf(v);
        else Cf[(size_t)(row + r) * N + col] = v;
      }
    }
  }
}

// ---------------- Per-head rank expansion -> bf16 [B,H,S,64] (Q and K) --------------
__global__ __launch_bounds__(256) void expand_head_qk(const float* __restrict__ t, int tstride,
                                                      const float* __restrict__ U,
                                                      const float* __restrict__ bias,
                                                      unsigned short* __restrict__ out) {
  __shared__ float Us[64][33];
  __shared__ float Ts[32][33];
  int blk = blockIdx.x;
  int sb = blk & 63;
  int h = (blk >> 6) & 15;
  int b = blk >> 10;
  int tid = threadIdx.x;
  for (int i = tid; i < 64 * 32; i += 256) Us[i >> 5][i & 31] = U[h * 2048 + i];
  for (int i = tid; i < 32 * 32; i += 256) {
    int sr = i >> 5, r = i & 31;
    Ts[sr][r] = t[(size_t)(b * Sc + sb * 32 + sr) * tstride + h * 32 + r];
  }
  __syncthreads();
  int e = tid & 63;
  int sg = tid >> 6;
  float bv = bias[h * 64 + e];
#pragma unroll
  for (int si = 0; si < 8; ++si) {
    int sr = sg * 8 + si;
    float acc = bv;
#pragma unroll
    for (int r = 0; r < 32; ++r) acc += Ts[sr][r] * Us[e][r];
    out[((size_t)((b * Hc + h) * Sc) + sb * 32 + sr) * 64 + e] = f2bf(acc);
  }
}

// ---------------- Per-head rank expansion -> bf16 TRANSPOSED [B,H,64,S] (V) ---------
__global__ __launch_bounds__(256) void expand_head_vT(const float* __restrict__ t, int tstride,
                                                      const float* __restrict__ U,
                                                      const float* __restrict__ bias,
                                                      unsigned short* __restrict__ out) {
  __shared__ float Us[64][33];
  __shared__ float Ts[32][33];
  int blk = blockIdx.x;
  int sb = blk & 63;
  int h = (blk >> 6) & 15;
  int b = blk >> 10;
  int tid = threadIdx.x;
  for (int i = tid; i < 64 * 32; i += 256) Us[i >> 5][i & 31] = U[h * 2048 + i];
  for (int i = tid; i < 32 * 32; i += 256) {
    int sr = i >> 5, r = i & 31;
    Ts[sr][r] = t[(size_t)(b * Sc + sb * 32 + sr) * tstride + h * 32 + r];
  }
  __syncthreads();
  int e = tid & 63;
  int sg = tid >> 6;
  float bv = bias[h * 64 + e];
  u16x8 v8;
#pragma unroll
  for (int si = 0; si < 8; ++si) {
    int sr = sg * 8 + si;
    float acc = bv;
#pragma unroll
    for (int r = 0; r < 32; ++r) acc += Ts[sr][r] * Us[e][r];
    v8[si] = f2bf(acc);
  }
  *(u16x8*)(out + ((size_t)((b * Hc + h) * Ec) + e) * Sc + sb * 32 + sg * 8) = v8;
}

// ---------------- Causal flash attention: swapped-QK^T 32x32 MFMA, lane-local SM ----
// 1 wave per block (64 thr). Wave = 32 q-rows, sweeps keys in 32-tiles.
// q,k: [B,H,S,64] bf16; vt: [B,H,64,S] bf16; out: [B,S,D] bf16.
// S^T = mfma32(K, Q^T): lane holds q-col (lane&31); 16 key-rows in regs.
__global__ __launch_bounds__(64) void attn_mfma(const unsigned short* __restrict__ q,
                                                const unsigned short* __restrict__ k,
                                                const unsigned short* __restrict__ vt,
                                                unsigned short* __restrict__ out) {
  int lane = threadIdx.x;
  int ll = lane & 31;
  int hi = lane >> 5;
  int blk = blockIdx.x;
  int qt = 63 - (blk >> 5);   // heaviest q-tiles dispatched first
  int bh = blk & 31;
  int b = bh >> 4, h = bh & 15;
  const unsigned short* qb = q + (size_t)bh * Sc * Ec;
  const unsigned short* kb = k + (size_t)bh * Sc * Ec;
  const unsigned short* vb = vt + (size_t)bh * Ec * Sc;
  int q0 = qt * 32;
  int nt = qt + 1;  // tiles of 32 keys, last is diagonal

  // Q^T B-fragments: col=q0+ll, k(e) = es*16 + hi*8 + j
  bf16x8 qf[4];
#pragma unroll
  for (int es = 0; es < 4; ++es)
    qf[es] = *(const bf16x8*)(qb + (size_t)(q0 + ll) * Ec + es * 16 + hi * 8);

  f32x16 accO[2] = {};  // O^T tiles: e=eo*32+erow(r,hi), q=ll
  float m = -1e30f, l = 0.f;

  // preload K fragments for tile 0: row=key=kbase+ll, k(e)=es*16+hi*8+j
  bf16x8 kf[4];
#pragma unroll
  for (int es = 0; es < 4; ++es)
    kf[es] = *(const bf16x8*)(kb + (size_t)ll * Ec + es * 16 + hi * 8);

#define ATT_BODY(kbase, MASK, PRELOAD)                                              \
  {                                                                                 \
    f32x16 c = {};                                                                  \
    __builtin_amdgcn_s_setprio(1);                                                  \
    c = MFMA32(kf[0], qf[0], c);                                                    \
    c = MFMA32(kf[1], qf[1], c);                                                    \
    c = MFMA32(kf[2], qf[2], c);                                                    \
    c = MFMA32(kf[3], qf[3], c);                                                    \
    __builtin_amdgcn_s_setprio(0);                                                  \
    bf16x8 kn[4];                                                                   \
    if (PRELOAD) {                                                                  \
      const unsigned short* kp = kb + (size_t)((kbase) + 32 + ll) * Ec + hi * 8;    \
      kn[0] = *(const bf16x8*)(kp);                                                 \
      kn[1] = *(const bf16x8*)(kp + 16);                                            \
      kn[2] = *(const bf16x8*)(kp + 32);                                            \
      kn[3] = *(const bf16x8*)(kp + 48);                                            \
    }                                                                               \
    bf16x8 vf[4];                                                                   \
    _Pragma("unroll") for (int ix = 0; ix < 4; ++ix) {                              \
      int eo = ix >> 1, h2 = ix & 1;                                                \
      vf[ix] = *(const bf16x8*)(vb + (size_t)(eo * 32 + ll) * Sc + (kbase) + h2 * 16 + hi * 8); \
    }                                                                               \
    float s[16];                                                                    \
    _Pragma("unroll") for (int r = 0; r < 16; ++r) {                                \
      s[r] = c[r] * SCLOG2E;                                                        \
      if (MASK) {                                                                   \
        int keyloc = (r & 3) + 8 * (r >> 2) + 4 * hi;                               \
        if (keyloc > ll) s[r] = -1e30f;                                             \
      }                                                                             \
    }                                                                               \
    float t0 = fmaxf(fmaxf(fmaxf(s[0], s[1]), fmaxf(s[2], s[3])),                   \
                     fmaxf(fmaxf(s[4], s[5]), fmaxf(s[6], s[7])));                  \
    float t1 = fmaxf(fmaxf(fmaxf(s[8], s[9]), fmaxf(s[10], s[11])),                 \
                     fmaxf(fmaxf(s[12], s[13]), fmaxf(s[14], s[15])));              \
    float tmax = fmaxf(t0, t1);                                                     \
    tmax = fmaxf(tmax, __shfl_xor(tmax, 32, 64));                                   \
    float mn = fmaxf(m, tmax);                                                      \
    float corr = exp2f(m - mn);                                                     \
    m = mn;                                                                         \
    float p[16];                                                                    \
    float lp = 0.f;                                                                 \
    _Pragma("unroll") for (int r = 0; r < 16; ++r) { p[r] = exp2f(s[r] - mn); lp += p[r]; } \
    l = l * corr + lp;                                                              \
    _Pragma("unroll") for (int r = 0; r < 16; ++r) { accO[0][r] *= corr; accO[1][r] *= corr; } \
    unsigned w0 = cvtpk(p[0], p[1]), w1 = cvtpk(p[2], p[3]);                        \
    unsigned w2 = cvtpk(p[4], p[5]), w3 = cvtpk(p[6], p[7]);                        \
    unsigned w4 = cvtpk(p[8], p[9]), w5 = cvtpk(p[10], p[11]);                      \
    unsigned w6 = cvtpk(p[12], p[13]), w7 = cvtpk(p[14], p[15]);                    \
    asm("v_permlane32_swap_b32 %0, %1" : "+v"(w0), "+v"(w2));                       \
    asm("v_permlane32_swap_b32 %0, %1" : "+v"(w1), "+v"(w3));                       \
    asm("v_permlane32_swap_b32 %0, %1" : "+v"(w4), "+v"(w6));                       \
    asm("v_permlane32_swap_b32 %0, %1" : "+v"(w5), "+v"(w7));                       \
    u32x4 pw0 = {w0, w1, w2, w3};                                                   \
    u32x4 pw1 = {w4, w5, w6, w7};                                                   \
    bf16x8 pb0 = __builtin_bit_cast(bf16x8, pw0);                                   \
    bf16x8 pb1 = __builtin_bit_cast(bf16x8, pw1);                                   \
    __builtin_amdgcn_s_setprio(1);                                                  \
    accO[0] = MFMA32(vf[0], pb0, accO[0]);                                          \
    accO[0] = MFMA32(vf[1], pb1, accO[0]);                                          \
    accO[1] = MFMA32(vf[2], pb0, accO[1]);                                          \
    accO[1] = MFMA32(vf[3], pb1, accO[1]);                                          \
    __builtin_amdgcn_s_setprio(0);                                                  \
    if (PRELOAD) { kf[0] = kn[0]; kf[1] = kn[1]; kf[2] = kn[2]; kf[3] = kn[3]; }    \
  }

  for (int t = 0; t < nt - 1; ++t) ATT_BODY(t * 32, false, true)
  ATT_BODY(q0, true, false)
#undef ATT_BODY

  float ltot = l + __shfl_xor(l, 32, 64);
  float inv = 1.f / ltot;
  unsigned short* orow = out + (size_t)(b * Sc + q0 + ll) * Dc + h * Ec;
#pragma unroll
  for (int eo = 0; eo < 2; ++eo)
#pragma unroll
    for (int r = 0; r < 16; ++r) {
      int e = eo * 32 + (r & 3) + 8 * (r >> 2) + 4 * hi;
      orow[e] = f2bf(accO[eo][r] * inv);
    }
}

extern "C" void kernel_launch(void* const* d_in, const int* in_sizes, int n_in,
                              void* d_out, int out_size, void* d_ws, size_t ws_size,
                              hipStream_t stream) {
  const float* hidden = (const float*)d_in[0];
  const float* ln1_w = (const float*)d_in[1];
  const float* ln1_b = (const float*)d_in[2];
  const float* q_U = (const float*)d_in[3];
  const float* q_V = (const float*)d_in[4];
  const float* q_bias = (const float*)d_in[5];
  const float* k_U = (const float*)d_in[6];
  const float* k_V = (const float*)d_in[7];
  const float* k_bias = (const float*)d_in[8];
  const float* v_U = (const float*)d_in[9];
  const float* v_V = (const float*)d_in[10];
  const float* v_bias = (const float*)d_in[11];
  const float* out_U = (const float*)d_in[12];
  const float* out_V = (const float*)d_in[13];
  const float* out_bias = (const float*)d_in[14];
  const float* ln2_w = (const float*)d_in[15];
  const float* ln2_b = (const float*)d_in[16];
  const float* fc1_U = (const float*)d_in[17];
  const float* fc1_V = (const float*)d_in[18];
  const float* fc1_bias = (const float*)d_in[19];
  const float* fc2_U = (const float*)d_in[20];
  const float* fc2_V = (const float*)d_in[21];
  const float* fc2_bias = (const float*)d_in[22];
  float* out = (float*)d_out;
  float* ws = (float*)d_ws;
  unsigned short* wsu = (unsigned short*)d_ws;

  // ---- bf16 weight arena (ushort offsets) ----
  unsigned short* wQKV = wsu;               // [1536,1024] (q_V|k_V|v_V)
  unsigned short* wKV = wsu + 524288;
  unsigned short* wVV = wsu + 1048576;
  unsigned short* wOUTV = wsu + 1572864;    // [512,1024]
  unsigned short* wOUTU = wsu + 2097152;    // [1024,512]
  unsigned short* wFC1V = wsu + 2621440;    // [512,1024]
  unsigned short* wFC1U = wsu + 3145728;    // [4096,512]
  unsigned short* wFC2V = wsu + 5242880;    // [512,4096]
  unsigned short* wFC2U = wsu + 7340032;    // [1024,512]

  // ---- activation arena (float offsets) ----
  float* h1 = ws + 4194304;                          // [4096,1024] fp32
  unsigned short* attn_out = (unsigned short*)(ws + 6291456);  // [4096,1024] bf16
  unsigned short* normed = (unsigned short*)(ws + 8388608);    // [4096,1024] bf16
  float* rb = ws + 10485760;                         // [4096,1536] fp32 (QKV t)
  unsigned short* rbB = (unsigned short*)(ws + 10485760);      // [4096,512] bf16
  unsigned short* ff = (unsigned short*)(ws + 11534336);       // [4096,4096] bf16
  unsigned short* qbuf = (unsigned short*)(ws + 16777216);
  unsigned short* kbuf = (unsigned short*)(ws + 18874368);
  unsigned short* rbG = (unsigned short*)(ws + 19922944);      // [4096,512] bf16
  unsigned short* vtbuf = (unsigned short*)(ws + 20971520);

  const int M = Bc * Sc;  // 4096
  dim3 blk(256);

  // ---- weight conversion ----
  convert3<<<1536, blk, 0, stream>>>(q_V, 524288, k_V, 524288, v_V, 524288, wQKV, wKV, wVV);
  convert3<<<1536, blk, 0, stream>>>(out_V, 524288, out_U, 524288, fc1_V, 524288, wOUTV, wOUTU, wFC1V);
  convert3<<<4608, blk, 0, stream>>>(fc1_U, 2097152, fc2_V, 2097152, fc2_U, 524288, wFC1U, wFC2V, wFC2U);

  // ---- LN1 ----
  ln_bf16<<<M, blk, 0, stream>>>(hidden, ln1_w, ln1_b, normed);

  // ---- fused QKV rank contraction: rb[4096,1536] = normed * [qV|kV|vV]^T ----
  gemm_bf16<64, 64><<<dim3(24, 64), blk, 0, stream>>>(normed, wQKV, rb, nullptr, nullptr, nullptr,
                                                      M, 1536, Dc, 0);
  expand_head_qk<<<2048, blk, 0, stream>>>(rb, 1536, q_U, q_bias, qbuf);
  expand_head_qk<<<2048, blk, 0, stream>>>(rb + 512, 1536, k_U, k_bias, kbuf);
  expand_head_vT<<<2048, blk, 0, stream>>>(rb + 1024, 1536, v_U, v_bias, vtbuf);

  // ---- causal attention -> attn_out (bf16) ----
  attn_mfma<<<2048, dim3(64), 0, stream>>>(qbuf, kbuf, vtbuf, attn_out);

  // ---- output projection + residual -> h1 (fp32) ----
  gemm_bf16<64, 64><<<dim3(8, 64), blk, 0, stream>>>(attn_out, wOUTV, nullptr, rbB, nullptr, nullptr,
                                                     M, 512, Dc, 0);
  gemm_bf16<64, 64><<<dim3(16, 64), blk, 0, stream>>>(rbB, wOUTU, h1, nullptr, out_bias, hidden,
                                                      M, Dc, 512, 0);

  // ---- LN2 + FF ----
  ln_bf16<<<M, blk, 0, stream>>>(h1, ln2_w, ln2_b, normed);
  gemm_bf16<64, 64><<<dim3(8, 64), blk, 0, stream>>>(normed, wFC1V, nullptr, rbB, nullptr, nullptr,
                                                     M, 512, Dc, 0);
  gemm_bf16<128, 128><<<dim3(32, 32), blk, 0, stream>>>(rbB, wFC1U, nullptr, ff, fc1_bias, nullptr,
                                                        M, DFFc, 512, 1);
  gemm_bf16<64, 64><<<dim3(8, 64), blk, 0, stream>>>(ff, wFC2V, nullptr, rbG, nullptr, nullptr,
                                                     M, 512, DFFc, 0);
  gemm_bf16<64, 64><<<dim3(16, 64), blk, 0, stream>>>(rbG, wFC2U, out, nullptr, fc2_bias, h1,
                                                      M, Dc, 512, 0);
}

// Round 5
// 354.327 us; speedup vs baseline: 6.2200x; 1.0107x over previous
//
#include <hip/hip_runtime.h>
#include <hip/hip_bf16.h>
#include <math.h>

#define Bc 2
#define Sc 2048
#define Dc 1024
#define Hc 16
#define Ec 64
#define DFFc 4096
#define SCALEc 0.125f
#define SCLOG2E 0.18033688f  /* SCALE * log2(e) */
#define LN_EPSc 1e-5f

typedef short bf16x8 __attribute__((ext_vector_type(8)));
typedef unsigned short u16x4 __attribute__((ext_vector_type(4)));
typedef unsigned short u16x8 __attribute__((ext_vector_type(8)));
typedef float f32x4 __attribute__((ext_vector_type(4)));
typedef float f32x16 __attribute__((ext_vector_type(16)));
typedef unsigned int u32x4 __attribute__((ext_vector_type(4)));
#define MFMA16(a, b, c) __builtin_amdgcn_mfma_f32_16x16x32_bf16(a, b, c, 0, 0, 0)
#define MFMA32(a, b, c) __builtin_amdgcn_mfma_f32_32x32x16_bf16(a, b, c, 0, 0, 0)
#define GLDS16(g, l)                                                            \
  __builtin_amdgcn_global_load_lds((const __attribute__((address_space(1))) void*)(g), \
                                   (__attribute__((address_space(3))) void*)(l), 16, 0, 0)

static __device__ __forceinline__ unsigned short f2bf(float x) {
  unsigned u = __float_as_uint(x);
  unsigned r = (u + 0x7FFFu + ((u >> 16) & 1u)) >> 16;
  return (unsigned short)r;
}
static __device__ __forceinline__ unsigned cvtpk(float lo, float hi) {
  unsigned r;
  asm("v_cvt_pk_bf16_f32 %0, %1, %2" : "=v"(r) : "v"(lo), "v"(hi));
  return r;
}

// ---------------- fp32 -> bf16 weight conversion, 3 tensors per launch -------------
__global__ __launch_bounds__(256) void convert3(const float* __restrict__ a, int na,
                                                const float* __restrict__ b, int nb,
                                                const float* __restrict__ c, int nc,
                                                unsigned short* __restrict__ oa,
                                                unsigned short* __restrict__ ob,
                                                unsigned short* __restrict__ oc) {
  int i = (blockIdx.x * 256 + threadIdx.x) * 4;
  const float* s;
  unsigned short* d;
  int off;
  if (i < na) { s = a; d = oa; off = i; }
  else if (i < na + nb) { s = b; d = ob; off = i - na; }
  else if (i < na + nb + nc) { s = c; d = oc; off = i - na - nb; }
  else return;
  float4 v = *(const float4*)(s + off);
  u16x4 o = {f2bf(v.x), f2bf(v.y), f2bf(v.z), f2bf(v.w)};
  *(u16x4*)(d + off) = o;
}

// ---------------- LayerNorm -> bf16 out ----------------
__global__ __launch_bounds__(256) void ln_bf16(const float* __restrict__ x,
                                               const float* __restrict__ w,
                                               const float* __restrict__ b,
                                               unsigned short* __restrict__ out) {
  __shared__ float sm[8];
  int row = blockIdx.x;
  int tid = threadIdx.x;
  const float* xr = x + (size_t)row * Dc;
  float v[4];
  float sum = 0.f;
#pragma unroll
  for (int i = 0; i < 4; ++i) { v[i] = xr[tid + i * 256]; sum += v[i]; }
#pragma unroll
  for (int off = 32; off > 0; off >>= 1) sum += __shfl_down(sum, off, 64);
  if ((tid & 63) == 0) sm[tid >> 6] = sum;
  __syncthreads();
  float mean = (sm[0] + sm[1] + sm[2] + sm[3]) * (1.f / Dc);
  float var = 0.f;
#pragma unroll
  for (int i = 0; i < 4; ++i) { float d0 = v[i] - mean; var += d0 * d0; }
#pragma unroll
  for (int off = 32; off > 0; off >>= 1) var += __shfl_down(var, off, 64);
  if ((tid & 63) == 0) sm[4 + (tid >> 6)] = var;
  __syncthreads();
  float rstd = rsqrtf((sm[4] + sm[5] + sm[6] + sm[7]) * (1.f / Dc) + LN_EPSc);
  unsigned short* orow = out + (size_t)row * Dc;
#pragma unroll
  for (int i = 0; i < 4; ++i) {
    int c = tid + i * 256;
    orow[c] = f2bf((v[i] - mean) * rstd * w[c] + b[c]);
  }
}

// ---------------- bf16 MFMA NT GEMM: C[M,N] = A[M,K] * W[N,K]^T -------------------
template <int BM, int BN>
__global__ __launch_bounds__(256) void gemm_bf16(const unsigned short* __restrict__ A,
                                                 const unsigned short* __restrict__ W,
                                                 float* __restrict__ Cf,
                                                 unsigned short* __restrict__ Cb,
                                                 const float* __restrict__ bias,
                                                 const float* __restrict__ res,
                                                 int M, int N, int K, int gelu) {
  constexpr int MT = BM / 32;
  constexpr int NT = BN / 32;
  __shared__ unsigned short As[BM * 32];
  __shared__ unsigned short Bs[BN * 32];
  int tid = threadIdx.x;
  int lane = tid & 63;
  int wid = tid >> 6;
  int cl = lane & 15, grp = lane >> 4;
  int wr = wid >> 1, wc = wid & 1;
  const unsigned short* Ab = A + (size_t)(blockIdx.y * BM) * K;
  const unsigned short* Wb = W + (size_t)(blockIdx.x * BN) * K;
  f32x4 acc[MT][NT];
  f32x4 z4 = {0.f, 0.f, 0.f, 0.f};
#pragma unroll
  for (int i = 0; i < MT; ++i)
#pragma unroll
    for (int j = 0; j < NT; ++j) acc[i][j] = z4;
  int r0 = tid >> 2;
  int g0 = (tid & 3) * 8;
  for (int k0 = 0; k0 < K; k0 += 32) {
    __syncthreads();
#pragma unroll
    for (int l = 0; l < BM / 64; ++l)
      GLDS16(Ab + (size_t)(r0 + l * 64) * K + k0 + g0, &As[(tid + l * 256) * 8]);
#pragma unroll
    for (int l = 0; l < BN / 64; ++l)
      GLDS16(Wb + (size_t)(r0 + l * 64) * K + k0 + g0, &Bs[(tid + l * 256) * 8]);
    __syncthreads();
    bf16x8 af[MT], bfr[NT];
#pragma unroll
    for (int i = 0; i < MT; ++i)
      af[i] = *(const bf16x8*)&As[(wr * (BM / 2) + i * 16 + cl) * 32 + grp * 8];
#pragma unroll
    for (int j = 0; j < NT; ++j)
      bfr[j] = *(const bf16x8*)&Bs[(wc * (BN / 2) + j * 16 + cl) * 32 + grp * 8];
#pragma unroll
    for (int i = 0; i < MT; ++i)
#pragma unroll
      for (int j = 0; j < NT; ++j) acc[i][j] = MFMA16(af[i], bfr[j], acc[i][j]);
  }
#pragma unroll
  for (int i = 0; i < MT; ++i) {
    int row = blockIdx.y * BM + wr * (BM / 2) + i * 16 + grp * 4;
#pragma unroll
    for (int j = 0; j < NT; ++j) {
      int col = blockIdx.x * BN + wc * (BN / 2) + j * 16 + cl;
      float bv = bias ? bias[col] : 0.f;
#pragma unroll
      for (int r = 0; r < 4; ++r) {
        float v = acc[i][j][r] + bv;
        if (gelu) v = 0.5f * v * (1.f + erff(v * 0.70710678118f));
        if (res) v += res[(size_t)(row + r) * N + col];
        if (Cb) Cb[(size_t)(row + r) * N + col] = f2bf(v);
        else Cf[(size_t)(row + r) * N + col] = v;
      }
    }
  }
}

// ---------------- Per-head rank expansion -> bf16 [B,H,S,64] (Q and K) --------------
__global__ __launch_bounds__(256) void expand_head_qk(const float* __restrict__ t, int tstride,
                                                      const float* __restrict__ U,
                                                      const float* __restrict__ bias,
                                                      unsigned short* __restrict__ out) {
  __shared__ float Us[64][33];
  __shared__ float Ts[32][33];
  int blk = blockIdx.x;
  int sb = blk & 63;
  int h = (blk >> 6) & 15;
  int b = blk >> 10;
  int tid = threadIdx.x;
  for (int i = tid; i < 64 * 32; i += 256) Us[i >> 5][i & 31] = U[h * 2048 + i];
  for (int i = tid; i < 32 * 32; i += 256) {
    int sr = i >> 5, r = i & 31;
    Ts[sr][r] = t[(size_t)(b * Sc + sb * 32 + sr) * tstride + h * 32 + r];
  }
  __syncthreads();
  int e = tid & 63;
  int sg = tid >> 6;
  float bv = bias[h * 64 + e];
#pragma unroll
  for (int si = 0; si < 8; ++si) {
    int sr = sg * 8 + si;
    float acc = bv;
#pragma unroll
    for (int r = 0; r < 32; ++r) acc += Ts[sr][r] * Us[e][r];
    out[((size_t)((b * Hc + h) * Sc) + sb * 32 + sr) * 64 + e] = f2bf(acc);
  }
}

// ---------------- Per-head rank expansion -> bf16 TRANSPOSED [B,H,64,S] (V) ---------
__global__ __launch_bounds__(256) void expand_head_vT(const float* __restrict__ t, int tstride,
                                                      const float* __restrict__ U,
                                                      const float* __restrict__ bias,
                                                      unsigned short* __restrict__ out) {
  __shared__ float Us[64][33];
  __shared__ float Ts[32][33];
  int blk = blockIdx.x;
  int sb = blk & 63;
  int h = (blk >> 6) & 15;
  int b = blk >> 10;
  int tid = threadIdx.x;
  for (int i = tid; i < 64 * 32; i += 256) Us[i >> 5][i & 31] = U[h * 2048 + i];
  for (int i = tid; i < 32 * 32; i += 256) {
    int sr = i >> 5, r = i & 31;
    Ts[sr][r] = t[(size_t)(b * Sc + sb * 32 + sr) * tstride + h * 32 + r];
  }
  __syncthreads();
  int e = tid & 63;
  int sg = tid >> 6;
  float bv = bias[h * 64 + e];
  u16x8 v8;
#pragma unroll
  for (int si = 0; si < 8; ++si) {
    int sr = sg * 8 + si;
    float acc = bv;
#pragma unroll
    for (int r = 0; r < 32; ++r) acc += Ts[sr][r] * Us[e][r];
    v8[si] = f2bf(acc);
  }
  *(u16x8*)(out + ((size_t)((b * Hc + h) * Ec) + e) * Sc + sb * 32 + sg * 8) = v8;
}

// ---------------- Causal flash attention: swapped-QK^T 32x32 MFMA ------------------
// 4 waves/block; wave w sweeps key-tiles [w*nt/4,(w+1)*nt/4) of this q-tile,
// independent online-softmax state; LDS merge at end (flash-decode combine).
// q,k: [B,H,S,64] bf16; vt: [B,H,64,S] bf16; out: [B,S,D] bf16.
__global__ __launch_bounds__(256) void attn_mfma(const unsigned short* __restrict__ q,
                                                 const unsigned short* __restrict__ k,
                                                 const unsigned short* __restrict__ vt,
                                                 unsigned short* __restrict__ out) {
  __shared__ float MS[3][34][64];
  int tid = threadIdx.x;
  int wid = tid >> 6;
  int lane = tid & 63;
  int ll = lane & 31;
  int hi = lane >> 5;
  int blk = blockIdx.x;
  int qt = 63 - (blk >> 5);   // heaviest q-tiles dispatched first
  int bh = blk & 31;
  int b = bh >> 4, h = bh & 15;
  const unsigned short* qb = q + (size_t)bh * Sc * Ec;
  const unsigned short* kb = k + (size_t)bh * Sc * Ec;
  const unsigned short* vb = vt + (size_t)bh * Ec * Sc;
  int q0 = qt * 32;
  int nt = qt + 1;
  int ts = wid * nt / 4;
  int te = (wid + 1) * nt / 4;

  // Q^T B-fragments: col=q0+ll, k(e) = es*16 + hi*8 + j
  bf16x8 qf[4];
#pragma unroll
  for (int es = 0; es < 4; ++es)
    qf[es] = *(const bf16x8*)(qb + (size_t)(q0 + ll) * Ec + es * 16 + hi * 8);

  f32x16 accO[2] = {};  // O^T tiles: e=eo*32+erow(r,hi), q=ll
  float m = -1e30f, l = 0.f;

  bf16x8 kf[4];
  if (ts < te) {
    const unsigned short* kp = kb + (size_t)(ts * 32 + ll) * Ec + hi * 8;
    kf[0] = *(const bf16x8*)(kp);
    kf[1] = *(const bf16x8*)(kp + 16);
    kf[2] = *(const bf16x8*)(kp + 32);
    kf[3] = *(const bf16x8*)(kp + 48);
  }

  for (int t = ts; t < te; ++t) {
    int kbase = t * 32;
    bool mask = (t == nt - 1);
    bool preload = (t + 1 < te);
    f32x16 c = {};
    __builtin_amdgcn_s_setprio(1);
    c = MFMA32(kf[0], qf[0], c);
    c = MFMA32(kf[1], qf[1], c);
    c = MFMA32(kf[2], qf[2], c);
    c = MFMA32(kf[3], qf[3], c);
    __builtin_amdgcn_s_setprio(0);
    bf16x8 kn[4];
    if (preload) {
      const unsigned short* kp = kb + (size_t)(kbase + 32 + ll) * Ec + hi * 8;
      kn[0] = *(const bf16x8*)(kp);
      kn[1] = *(const bf16x8*)(kp + 16);
      kn[2] = *(const bf16x8*)(kp + 32);
      kn[3] = *(const bf16x8*)(kp + 48);
    }
    bf16x8 vf[4];
#pragma unroll
    for (int ix = 0; ix < 4; ++ix) {
      int eo = ix >> 1, h2 = ix & 1;
      vf[ix] = *(const bf16x8*)(vb + (size_t)(eo * 32 + ll) * Sc + kbase + h2 * 16 + hi * 8);
    }
    float s[16];
#pragma unroll
    for (int r = 0; r < 16; ++r) s[r] = c[r] * SCLOG2E;
    if (mask) {
#pragma unroll
      for (int r = 0; r < 16; ++r) {
        int keyloc = (r & 3) + 8 * (r >> 2) + 4 * hi;
        if (keyloc > ll) s[r] = -1e30f;
      }
    }
    float u0 = fmaxf(fmaxf(fmaxf(s[0], s[1]), fmaxf(s[2], s[3])),
                     fmaxf(fmaxf(s[4], s[5]), fmaxf(s[6], s[7])));
    float u1 = fmaxf(fmaxf(fmaxf(s[8], s[9]), fmaxf(s[10], s[11])),
                     fmaxf(fmaxf(s[12], s[13]), fmaxf(s[14], s[15])));
    float tmax = fmaxf(u0, u1);
    tmax = fmaxf(tmax, __shfl_xor(tmax, 32, 64));
    if (!__all(tmax <= m)) {  // defer-max: skip rescale when no lane's max grew
      float mn = fmaxf(m, tmax);
      float corr = exp2f(m - mn);
      m = mn;
      l *= corr;
#pragma unroll
      for (int r = 0; r < 16; ++r) { accO[0][r] *= corr; accO[1][r] *= corr; }
    }
    float p[16];
    float lp = 0.f;
#pragma unroll
    for (int r = 0; r < 16; ++r) { p[r] = exp2f(s[r] - m); lp += p[r]; }
    l += lp;
    unsigned w0 = cvtpk(p[0], p[1]), w1 = cvtpk(p[2], p[3]);
    unsigned w2 = cvtpk(p[4], p[5]), w3 = cvtpk(p[6], p[7]);
    unsigned w4 = cvtpk(p[8], p[9]), w5 = cvtpk(p[10], p[11]);
    unsigned w6 = cvtpk(p[12], p[13]), w7 = cvtpk(p[14], p[15]);
    asm("v_permlane32_swap_b32 %0, %1" : "+v"(w0), "+v"(w2));
    asm("v_permlane32_swap_b32 %0, %1" : "+v"(w1), "+v"(w3));
    asm("v_permlane32_swap_b32 %0, %1" : "+v"(w4), "+v"(w6));
    asm("v_permlane32_swap_b32 %0, %1" : "+v"(w5), "+v"(w7));
    u32x4 pw0 = {w0, w1, w2, w3};
    u32x4 pw1 = {w4, w5, w6, w7};
    bf16x8 pb0 = __builtin_bit_cast(bf16x8, pw0);
    bf16x8 pb1 = __builtin_bit_cast(bf16x8, pw1);
    __builtin_amdgcn_s_setprio(1);
    accO[0] = MFMA32(vf[0], pb0, accO[0]);
    accO[0] = MFMA32(vf[1], pb1, accO[0]);
    accO[1] = MFMA32(vf[2], pb0, accO[1]);
    accO[1] = MFMA32(vf[3], pb1, accO[1]);
    __builtin_amdgcn_s_setprio(0);
    if (preload) { kf[0] = kn[0]; kf[1] = kn[1]; kf[2] = kn[2]; kf[3] = kn[3]; }
  }

  // ---- merge 4 partial (m, l, O) states ----
  if (wid) {
#pragma unroll
    for (int r = 0; r < 16; ++r) {
      MS[wid - 1][r][lane] = accO[0][r];
      MS[wid - 1][16 + r][lane] = accO[1][r];
    }
    MS[wid - 1][32][lane] = m;
    MS[wid - 1][33][lane] = l;
  }
  __syncthreads();
  if (wid == 0) {
    float mstar = m;
#pragma unroll
    for (int w = 0; w < 3; ++w) mstar = fmaxf(mstar, MS[w][32][lane]);
    float sc = exp2f(m - mstar);
    l *= sc;
#pragma unroll
    for (int r = 0; r < 16; ++r) { accO[0][r] *= sc; accO[1][r] *= sc; }
#pragma unroll
    for (int w = 0; w < 3; ++w) {
      float mw = MS[w][32][lane];
      float lw = MS[w][33][lane];
      float sw = exp2f(mw - mstar);
      l += lw * sw;
#pragma unroll
      for (int r = 0; r < 16; ++r) {
        accO[0][r] += MS[w][r][lane] * sw;
        accO[1][r] += MS[w][16 + r][lane] * sw;
      }
    }
    float ltot = l + __shfl_xor(l, 32, 64);
    float inv = 1.f / ltot;
    unsigned short* orow = out + (size_t)(b * Sc + q0 + ll) * Dc + h * Ec;
#pragma unroll
    for (int eo = 0; eo < 2; ++eo)
#pragma unroll
      for (int r = 0; r < 16; ++r) {
        int e = eo * 32 + (r & 3) + 8 * (r >> 2) + 4 * hi;
        orow[e] = f2bf(accO[eo][r] * inv);
      }
  }
}

extern "C" void kernel_launch(void* const* d_in, const int* in_sizes, int n_in,
                              void* d_out, int out_size, void* d_ws, size_t ws_size,
                              hipStream_t stream) {
  const float* hidden = (const float*)d_in[0];
  const float* ln1_w = (const float*)d_in[1];
  const float* ln1_b = (const float*)d_in[2];
  const float* q_U = (const float*)d_in[3];
  const float* q_V = (const float*)d_in[4];
  const float* q_bias = (const float*)d_in[5];
  const float* k_U = (const float*)d_in[6];
  const float* k_V = (const float*)d_in[7];
  const float* k_bias = (const float*)d_in[8];
  const float* v_U = (const float*)d_in[9];
  const float* v_V = (const float*)d_in[10];
  const float* v_bias = (const float*)d_in[11];
  const float* out_U = (const float*)d_in[12];
  const float* out_V = (const float*)d_in[13];
  const float* out_bias = (const float*)d_in[14];
  const float* ln2_w = (const float*)d_in[15];
  const float* ln2_b = (const float*)d_in[16];
  const float* fc1_U = (const float*)d_in[17];
  const float* fc1_V = (const float*)d_in[18];
  const float* fc1_bias = (const float*)d_in[19];
  const float* fc2_U = (const float*)d_in[20];
  const float* fc2_V = (const float*)d_in[21];
  const float* fc2_bias = (const float*)d_in[22];
  float* out = (float*)d_out;
  float* ws = (float*)d_ws;
  unsigned short* wsu = (unsigned short*)d_ws;

  // ---- bf16 weight arena (ushort offsets) ----
  unsigned short* wQKV = wsu;               // [1536,1024] (q_V|k_V|v_V)
  unsigned short* wKV = wsu + 524288;
  unsigned short* wVV = wsu + 1048576;
  unsigned short* wOUTV = wsu + 1572864;    // [512,1024]
  unsigned short* wOUTU = wsu + 2097152;    // [1024,512]
  unsigned short* wFC1V = wsu + 2621440;    // [512,1024]
  unsigned short* wFC1U = wsu + 3145728;    // [4096,512]
  unsigned short* wFC2V = wsu + 5242880;    // [512,4096]
  unsigned short* wFC2U = wsu + 7340032;    // [1024,512]

  // ---- activation arena (float offsets) ----
  float* h1 = ws + 4194304;                          // [4096,1024] fp32
  unsigned short* attn_out = (unsigned short*)(ws + 6291456);  // [4096,1024] bf16
  unsigned short* normed = (unsigned short*)(ws + 8388608);    // [4096,1024] bf16
  float* rb = ws + 10485760;                         // [4096,1536] fp32 (QKV t)
  unsigned short* rbB = (unsigned short*)(ws + 10485760);      // [4096,512] bf16
  unsigned short* ff = (unsigned short*)(ws + 11534336);       // [4096,4096] bf16
  unsigned short* qbuf = (unsigned short*)(ws + 16777216);
  unsigned short* kbuf = (unsigned short*)(ws + 18874368);
  unsigned short* rbG = (unsigned short*)(ws + 19922944);      // [4096,512] bf16
  unsigned short* vtbuf = (unsigned short*)(ws + 20971520);

  const int M = Bc * Sc;  // 4096
  dim3 blk(256);

  // ---- weight conversion ----
  convert3<<<1536, blk, 0, stream>>>(q_V, 524288, k_V, 524288, v_V, 524288, wQKV, wKV, wVV);
  convert3<<<1536, blk, 0, stream>>>(out_V, 524288, out_U, 524288, fc1_V, 524288, wOUTV, wOUTU, wFC1V);
  convert3<<<4608, blk, 0, stream>>>(fc1_U, 2097152, fc2_V, 2097152, fc2_U, 524288, wFC1U, wFC2V, wFC2U);

  // ---- LN1 ----
  ln_bf16<<<M, blk, 0, stream>>>(hidden, ln1_w, ln1_b, normed);

  // ---- fused QKV rank contraction: rb[4096,1536] = normed * [qV|kV|vV]^T ----
  gemm_bf16<64, 64><<<dim3(24, 64), blk, 0, stream>>>(normed, wQKV, rb, nullptr, nullptr, nullptr,
                                                      M, 1536, Dc, 0);
  expand_head_qk<<<2048, blk, 0, stream>>>(rb, 1536, q_U, q_bias, qbuf);
  expand_head_qk<<<2048, blk, 0, stream>>>(rb + 512, 1536, k_U, k_bias, kbuf);
  expand_head_vT<<<2048, blk, 0, stream>>>(rb + 1024, 1536, v_U, v_bias, vtbuf);

  // ---- causal attention -> attn_out (bf16) ----
  attn_mfma<<<2048, blk, 0, stream>>>(qbuf, kbuf, vtbuf, attn_out);

  // ---- output projection + residual -> h1 (fp32) ----
  gemm_bf16<64, 64><<<dim3(8, 64), blk, 0, stream>>>(attn_out, wOUTV, nullptr, rbB, nullptr, nullptr,
                                                     M, 512, Dc, 0);
  gemm_bf16<64, 64><<<dim3(16, 64), blk, 0, stream>>>(rbB, wOUTU, h1, nullptr, out_bias, hidden,
                                                      M, Dc, 512, 0);

  // ---- LN2 + FF ----
  ln_bf16<<<M, blk, 0, stream>>>(h1, ln2_w, ln2_b, normed);
  gemm_bf16<64, 64><<<dim3(8, 64), blk, 0, stream>>>(normed, wFC1V, nullptr, rbB, nullptr, nullptr,
                                                     M, 512, Dc, 0);
  gemm_bf16<128, 128><<<dim3(32, 32), blk, 0, stream>>>(rbB, wFC1U, nullptr, ff, fc1_bias, nullptr,
                                                        M, DFFc, 512, 1);
  gemm_bf16<64, 64><<<dim3(8, 64), blk, 0, stream>>>(ff, wFC2V, nullptr, rbG, nullptr, nullptr,
                                                     M, 512, DFFc, 0);
  gemm_bf16<64, 64><<<dim3(16, 64), blk, 0, stream>>>(rbG, wFC2U, out, nullptr, fc2_bias, h1,
                                                      M, Dc, 512, 0);
}

// Round 6
// 300.675 us; speedup vs baseline: 7.3299x; 1.1784x over previous
//
#include <hip/hip_runtime.h>
#include <hip/hip_bf16.h>
#include <math.h>

#define Bc 2
#define Sc 2048
#define Dc 1024
#define Hc 16
#define Ec 64
#define DFFc 4096
#define SCALEc 0.125f
#define SCLOG2E 0.18033688f  /* SCALE * log2(e) */
#define LN_EPSc 1e-5f
#define BH_STRIDE 131072     /* 2048*64 elems per (b,h) slice */

typedef short bf16x8 __attribute__((ext_vector_type(8)));
typedef unsigned short u16x4 __attribute__((ext_vector_type(4)));
typedef unsigned short u16x8 __attribute__((ext_vector_type(8)));
typedef float f32x4 __attribute__((ext_vector_type(4)));
typedef float f32x16 __attribute__((ext_vector_type(16)));
typedef unsigned int u32x4 __attribute__((ext_vector_type(4)));
#define MFMA16(a, b, c) __builtin_amdgcn_mfma_f32_16x16x32_bf16(a, b, c, 0, 0, 0)
#define MFMA32(a, b, c) __builtin_amdgcn_mfma_f32_32x32x16_bf16(a, b, c, 0, 0, 0)
#define GLDS16(g, l)                                                            \
  __builtin_amdgcn_global_load_lds((const __attribute__((address_space(1))) void*)(g), \
                                   (__attribute__((address_space(3))) void*)(l), 16, 0, 0)

static __device__ __forceinline__ unsigned short f2bf(float x) {
  unsigned u = __float_as_uint(x);
  unsigned r = (u + 0x7FFFu + ((u >> 16) & 1u)) >> 16;
  return (unsigned short)r;
}
static __device__ __forceinline__ unsigned cvtpk(float lo, float hi) {
  unsigned r;
  asm("v_cvt_pk_bf16_f32 %0, %1, %2" : "=v"(r) : "v"(lo), "v"(hi));
  return r;
}

// ---------------- fp32 -> bf16 weight conversion, 3 tensors per launch -------------
__global__ __launch_bounds__(256) void convert3(const float* __restrict__ a, int na,
                                                const float* __restrict__ b, int nb,
                                                const float* __restrict__ c, int nc,
                                                unsigned short* __restrict__ oa,
                                                unsigned short* __restrict__ ob,
                                                unsigned short* __restrict__ oc) {
  int i = (blockIdx.x * 256 + threadIdx.x) * 4;
  const float* s;
  unsigned short* d;
  int off;
  if (i < na) { s = a; d = oa; off = i; }
  else if (i < na + nb) { s = b; d = ob; off = i - na; }
  else if (i < na + nb + nc) { s = c; d = oc; off = i - na - nb; }
  else return;
  float4 v = *(const float4*)(s + off);
  u16x4 o = {f2bf(v.x), f2bf(v.y), f2bf(v.z), f2bf(v.w)};
  *(u16x4*)(d + off) = o;
}

// ---------------- LayerNorm -> bf16 out ----------------
__global__ __launch_bounds__(256) void ln_bf16(const float* __restrict__ x,
                                               const float* __restrict__ w,
                                               const float* __restrict__ b,
                                               unsigned short* __restrict__ out) {
  __shared__ float sm[8];
  int row = blockIdx.x;
  int tid = threadIdx.x;
  const float* xr = x + (size_t)row * Dc;
  float v[4];
  float sum = 0.f;
#pragma unroll
  for (int i = 0; i < 4; ++i) { v[i] = xr[tid + i * 256]; sum += v[i]; }
#pragma unroll
  for (int off = 32; off > 0; off >>= 1) sum += __shfl_down(sum, off, 64);
  if ((tid & 63) == 0) sm[tid >> 6] = sum;
  __syncthreads();
  float mean = (sm[0] + sm[1] + sm[2] + sm[3]) * (1.f / Dc);
  float var = 0.f;
#pragma unroll
  for (int i = 0; i < 4; ++i) { float d0 = v[i] - mean; var += d0 * d0; }
#pragma unroll
  for (int off = 32; off > 0; off >>= 1) var += __shfl_down(var, off, 64);
  if ((tid & 63) == 0) sm[4 + (tid >> 6)] = var;
  __syncthreads();
  float rstd = rsqrtf((sm[4] + sm[5] + sm[6] + sm[7]) * (1.f / Dc) + LN_EPSc);
  unsigned short* orow = out + (size_t)row * Dc;
#pragma unroll
  for (int i = 0; i < 4; ++i) {
    int c = tid + i * 256;
    orow[c] = f2bf((v[i] - mean) * rstd * w[c] + b[c]);
  }
}

// ---------------- bf16 MFMA NT GEMM: C[M,N] = A[M,K] * W[N,K]^T -------------------
// BMxBN tile, BK=64, 256 threads (4 waves, 2x2). global_load_lds width 16 with
// pre-swizzled source (col ^= (row&7)*8 elems) + same XOR on ds_read (T2, rule 21).
template <int BM, int BN>
__global__ __launch_bounds__(256) void gemm_bf16(const unsigned short* __restrict__ A,
                                                 const unsigned short* __restrict__ W,
                                                 float* __restrict__ Cf,
                                                 unsigned short* __restrict__ Cb,
                                                 const float* __restrict__ bias,
                                                 const float* __restrict__ res,
                                                 int M, int N, int K, int gelu) {
  constexpr int BK = 64;
  constexpr int MT = BM / 32;
  constexpr int NT = BN / 32;
  __shared__ unsigned short As[BM * BK];
  __shared__ unsigned short Bs[BN * BK];
  int tid = threadIdx.x;
  int lane = tid & 63;
  int wid = tid >> 6;
  int cl = lane & 15, grp = lane >> 4;
  int wr = wid >> 1, wc = wid & 1;
  const unsigned short* Ab = A + (size_t)(blockIdx.y * BM) * K;
  const unsigned short* Wb = W + (size_t)(blockIdx.x * BN) * K;
  f32x4 acc[MT][NT];
  f32x4 z4 = {0.f, 0.f, 0.f, 0.f};
#pragma unroll
  for (int i = 0; i < MT; ++i)
#pragma unroll
    for (int j = 0; j < NT; ++j) acc[i][j] = z4;
  int r0 = tid >> 3;              // staging row (0..31)
  int c0 = (tid & 7) * 8;         // staging col chunk (elements)
  for (int k0 = 0; k0 < K; k0 += BK) {
    __syncthreads();
#pragma unroll
    for (int l = 0; l < BM / 32; ++l) {
      int row = r0 + l * 32;
      int sc = c0 ^ ((row & 7) * 8);
      GLDS16(Ab + (size_t)row * K + k0 + sc, &As[(tid + l * 256) * 8]);
    }
#pragma unroll
    for (int l = 0; l < BN / 32; ++l) {
      int row = r0 + l * 32;
      int sc = c0 ^ ((row & 7) * 8);
      GLDS16(Wb + (size_t)row * K + k0 + sc, &Bs[(tid + l * 256) * 8]);
    }
    __syncthreads();
#pragma unroll
    for (int kk = 0; kk < 2; ++kk) {
      bf16x8 af[MT], bfr[NT];
#pragma unroll
      for (int i = 0; i < MT; ++i) {
        int row = wr * (BM / 2) + i * 16 + cl;
        af[i] = *(const bf16x8*)&As[row * BK + ((kk * 32 + grp * 8) ^ ((row & 7) * 8))];
      }
#pragma unroll
      for (int j = 0; j < NT; ++j) {
        int row = wc * (BN / 2) + j * 16 + cl;
        bfr[j] = *(const bf16x8*)&Bs[row * BK + ((kk * 32 + grp * 8) ^ ((row & 7) * 8))];
      }
#pragma unroll
      for (int i = 0; i < MT; ++i)
#pragma unroll
        for (int j = 0; j < NT; ++j) acc[i][j] = MFMA16(af[i], bfr[j], acc[i][j]);
    }
  }
#pragma unroll
  for (int i = 0; i < MT; ++i) {
    int row = blockIdx.y * BM + wr * (BM / 2) + i * 16 + grp * 4;
#pragma unroll
    for (int j = 0; j < NT; ++j) {
      int col = blockIdx.x * BN + wc * (BN / 2) + j * 16 + cl;
      float bv = bias ? bias[col] : 0.f;
#pragma unroll
      for (int r = 0; r < 4; ++r) {
        float v = acc[i][j][r] + bv;
        if (gelu) v = 0.5f * v * (1.f + erff(v * 0.70710678118f));
        if (res) v += res[(size_t)(row + r) * N + col];
        if (Cb) Cb[(size_t)(row + r) * N + col] = f2bf(v);
        else Cf[(size_t)(row + r) * N + col] = v;
      }
    }
  }
}

// ---------------- Per-head rank expansion -> FRAGMENT-PACKED bf16 (Q and K) --------
// out[bh][tile][es][lane][8]: element (s,e) at tile=s>>5, lane=(s&31)+((e>>3)&1)*32,
// es=e>>4, j=e&7. Thread = (s, e-chunk): one contiguous u16x8 store.
__global__ __launch_bounds__(256) void expand_head_qk_frag(const float* __restrict__ t, int tstride,
                                                           const float* __restrict__ U,
                                                           const float* __restrict__ bias,
                                                           unsigned short* __restrict__ out) {
  __shared__ float Us[64][33];
  __shared__ float Ts[32][33];
  int blk = blockIdx.x;
  int sb = blk & 63;
  int h = (blk >> 6) & 15;
  int b = blk >> 10;
  int bh = b * Hc + h;
  int tid = threadIdx.x;
  for (int i = tid; i < 64 * 32; i += 256) Us[i >> 5][i & 31] = U[h * 2048 + i];
  for (int i = tid; i < 32 * 32; i += 256) {
    int sr = i >> 5, r = i & 31;
    Ts[sr][r] = t[(size_t)(b * Sc + sb * 32 + sr) * tstride + h * 32 + r];
  }
  __syncthreads();
  int s = tid >> 3;   // 0..31 (row within tile sb)
  int ec = tid & 7;   // e-chunk
  float acc[8];
#pragma unroll
  for (int j = 0; j < 8; ++j) acc[j] = bias[h * 64 + ec * 8 + j];
  for (int r = 0; r < 32; ++r) {
    float tv = Ts[s][r];
#pragma unroll
    for (int j = 0; j < 8; ++j) acc[j] += tv * Us[ec * 8 + j][r];
  }
  u16x8 v8;
#pragma unroll
  for (int j = 0; j < 8; ++j) v8[j] = f2bf(acc[j]);
  int es = ec >> 1, hi = ec & 1;
  int lane = s + hi * 32;
  *(u16x8*)(out + (size_t)bh * BH_STRIDE + (size_t)(((sb * 4 + es) * 64 + lane)) * 8) = v8;
}

// ---------------- Per-head rank expansion -> FRAGMENT-PACKED transposed V ----------
// out[bh][tile][ix][lane][8]: element (e,key) at tile=key>>5, ix=(e>>5)*2+((key>>4)&1),
// lane=(e&31)+((key>>3)&1)*32, j=key&7. Thread = (e, key-chunk): contiguous store.
__global__ __launch_bounds__(256) void expand_head_vT_frag(const float* __restrict__ t, int tstride,
                                                           const float* __restrict__ U,
                                                           const float* __restrict__ bias,
                                                           unsigned short* __restrict__ out) {
  __shared__ float Us[64][33];
  __shared__ float Ts[32][33];
  int blk = blockIdx.x;
  int sb = blk & 63;
  int h = (blk >> 6) & 15;
  int b = blk >> 10;
  int bh = b * Hc + h;
  int tid = threadIdx.x;
  for (int i = tid; i < 64 * 32; i += 256) Us[i >> 5][i & 31] = U[h * 2048 + i];
  for (int i = tid; i < 32 * 32; i += 256) {
    int sr = i >> 5, r = i & 31;
    Ts[sr][r] = t[(size_t)(b * Sc + sb * 32 + sr) * tstride + h * 32 + r];
  }
  __syncthreads();
  int e = tid & 63;
  int sg = tid >> 6;
  float bv = bias[h * 64 + e];
  u16x8 v8;
#pragma unroll
  for (int si = 0; si < 8; ++si) {
    int sr = sg * 8 + si;
    float acc = bv;
#pragma unroll
    for (int r = 0; r < 32; ++r) acc += Ts[sr][r] * Us[e][r];
    v8[si] = f2bf(acc);
  }
  int eo = e >> 5, ll = e & 31;
  int h2 = sg >> 1, hi = sg & 1;
  int ix = eo * 2 + h2;
  int lane = ll + hi * 32;
  *(u16x8*)(out + (size_t)bh * BH_STRIDE + (size_t)(((sb * 4 + ix) * 64 + lane)) * 8) = v8;
}

// ---------------- Causal flash attention: swapped-QK^T 32x32 MFMA ------------------
// Fragment-packed inputs: every hot-loop load is base + lane*16B (fully coalesced).
// 4 waves/block; wave w sweeps key-tiles [w*nt/4,(w+1)*nt/4); LDS merge at end.
__global__ __launch_bounds__(256) void attn_mfma(const unsigned short* __restrict__ qf_,
                                                 const unsigned short* __restrict__ kf_,
                                                 const unsigned short* __restrict__ vf_,
                                                 unsigned short* __restrict__ out) {
  __shared__ float MS[3][34][64];
  int tid = threadIdx.x;
  int wid = tid >> 6;
  int lane = tid & 63;
  int ll = lane & 31;
  int hi = lane >> 5;
  int blk = blockIdx.x;
  int qt = 63 - (blk >> 5);   // heaviest q-tiles dispatched first
  int bh = blk & 31;
  int b = bh >> 4, h = bh & 15;
  const unsigned short* qb = qf_ + (size_t)bh * BH_STRIDE;
  const unsigned short* kb = kf_ + (size_t)bh * BH_STRIDE;
  const unsigned short* vb = vf_ + (size_t)bh * BH_STRIDE;
  int q0 = qt * 32;
  int nt = qt + 1;
  int ts = wid * nt / 4;
  int te = (wid + 1) * nt / 4;

  bf16x8 qf[4];
#pragma unroll
  for (int es = 0; es < 4; ++es)
    qf[es] = *(const bf16x8*)(qb + (size_t)((qt * 4 + es) * 64 + lane) * 8);

  f32x16 accO[2] = {};
  float m = -1e30f, l = 0.f;

  bf16x8 kf[4];
  if (ts < te) {
#pragma unroll
    for (int es = 0; es < 4; ++es)
      kf[es] = *(const bf16x8*)(kb + (size_t)((ts * 4 + es) * 64 + lane) * 8);
  }

  for (int t = ts; t < te; ++t) {
    bool mask = (t == nt - 1);
    bool preload = (t + 1 < te);
    f32x16 c = {};
    __builtin_amdgcn_s_setprio(1);
    c = MFMA32(kf[0], qf[0], c);
    c = MFMA32(kf[1], qf[1], c);
    c = MFMA32(kf[2], qf[2], c);
    c = MFMA32(kf[3], qf[3], c);
    __builtin_amdgcn_s_setprio(0);
    bf16x8 kn[4];
    if (preload) {
#pragma unroll
      for (int es = 0; es < 4; ++es)
        kn[es] = *(const bf16x8*)(kb + (size_t)(((t + 1) * 4 + es) * 64 + lane) * 8);
    }
    bf16x8 vf[4];
#pragma unroll
    for (int ix = 0; ix < 4; ++ix)
      vf[ix] = *(const bf16x8*)(vb + (size_t)((t * 4 + ix) * 64 + lane) * 8);
    float s[16];
#pragma unroll
    for (int r = 0; r < 16; ++r) s[r] = c[r] * SCLOG2E;
    if (mask) {
#pragma unroll
      for (int r = 0; r < 16; ++r) {
        int keyloc = (r & 3) + 8 * (r >> 2) + 4 * hi;
        if (keyloc > ll) s[r] = -1e30f;
      }
    }
    float u0 = fmaxf(fmaxf(fmaxf(s[0], s[1]), fmaxf(s[2], s[3])),
                     fmaxf(fmaxf(s[4], s[5]), fmaxf(s[6], s[7])));
    float u1 = fmaxf(fmaxf(fmaxf(s[8], s[9]), fmaxf(s[10], s[11])),
                     fmaxf(fmaxf(s[12], s[13]), fmaxf(s[14], s[15])));
    float tmax = fmaxf(u0, u1);
    tmax = fmaxf(tmax, __shfl_xor(tmax, 32, 64));
    if (!__all(tmax <= m)) {  // defer-max
      float mn = fmaxf(m, tmax);
      float corr = exp2f(m - mn);
      m = mn;
      l *= corr;
#pragma unroll
      for (int r = 0; r < 16; ++r) { accO[0][r] *= corr; accO[1][r] *= corr; }
    }
    float p[16];
    float lp = 0.f;
#pragma unroll
    for (int r = 0; r < 16; ++r) { p[r] = exp2f(s[r] - m); lp += p[r]; }
    l += lp;
    unsigned w0 = cvtpk(p[0], p[1]), w1 = cvtpk(p[2], p[3]);
    unsigned w2 = cvtpk(p[4], p[5]), w3 = cvtpk(p[6], p[7]);
    unsigned w4 = cvtpk(p[8], p[9]), w5 = cvtpk(p[10], p[11]);
    unsigned w6 = cvtpk(p[12], p[13]), w7 = cvtpk(p[14], p[15]);
    asm("v_permlane32_swap_b32 %0, %1" : "+v"(w0), "+v"(w2));
    asm("v_permlane32_swap_b32 %0, %1" : "+v"(w1), "+v"(w3));
    asm("v_permlane32_swap_b32 %0, %1" : "+v"(w4), "+v"(w6));
    asm("v_permlane32_swap_b32 %0, %1" : "+v"(w5), "+v"(w7));
    u32x4 pw0 = {w0, w1, w2, w3};
    u32x4 pw1 = {w4, w5, w6, w7};
    bf16x8 pb0 = __builtin_bit_cast(bf16x8, pw0);
    bf16x8 pb1 = __builtin_bit_cast(bf16x8, pw1);
    __builtin_amdgcn_s_setprio(1);
    accO[0] = MFMA32(vf[0], pb0, accO[0]);
    accO[0] = MFMA32(vf[1], pb1, accO[0]);
    accO[1] = MFMA32(vf[2], pb0, accO[1]);
    accO[1] = MFMA32(vf[3], pb1, accO[1]);
    __builtin_amdgcn_s_setprio(0);
    if (preload) { kf[0] = kn[0]; kf[1] = kn[1]; kf[2] = kn[2]; kf[3] = kn[3]; }
  }

  // ---- merge 4 partial (m, l, O) states ----
  if (wid) {
#pragma unroll
    for (int r = 0; r < 16; ++r) {
      MS[wid - 1][r][lane] = accO[0][r];
      MS[wid - 1][16 + r][lane] = accO[1][r];
    }
    MS[wid - 1][32][lane] = m;
    MS[wid - 1][33][lane] = l;
  }
  __syncthreads();
  if (wid == 0) {
    float mstar = m;
#pragma unroll
    for (int w = 0; w < 3; ++w) mstar = fmaxf(mstar, MS[w][32][lane]);
    float sc = exp2f(m - mstar);
    l *= sc;
#pragma unroll
    for (int r = 0; r < 16; ++r) { accO[0][r] *= sc; accO[1][r] *= sc; }
#pragma unroll
    for (int w = 0; w < 3; ++w) {
      float mw = MS[w][32][lane];
      float lw = MS[w][33][lane];
      float sw = exp2f(mw - mstar);
      l += lw * sw;
#pragma unroll
      for (int r = 0; r < 16; ++r) {
        accO[0][r] += MS[w][r][lane] * sw;
        accO[1][r] += MS[w][16 + r][lane] * sw;
      }
    }
    float ltot = l + __shfl_xor(l, 32, 64);
    float inv = 1.f / ltot;
    unsigned short* orow = out + (size_t)(b * Sc + q0 + ll) * Dc + h * Ec;
#pragma unroll
    for (int eo = 0; eo < 2; ++eo)
#pragma unroll
      for (int r = 0; r < 16; ++r) {
        int e = eo * 32 + (r & 3) + 8 * (r >> 2) + 4 * hi;
        orow[e] = f2bf(accO[eo][r] * inv);
      }
  }
}

extern "C" void kernel_launch(void* const* d_in, const int* in_sizes, int n_in,
                              void* d_out, int out_size, void* d_ws, size_t ws_size,
                              hipStream_t stream) {
  const float* hidden = (const float*)d_in[0];
  const float* ln1_w = (const float*)d_in[1];
  const float* ln1_b = (const float*)d_in[2];
  const float* q_U = (const float*)d_in[3];
  const float* q_V = (const float*)d_in[4];
  const float* q_bias = (const float*)d_in[5];
  const float* k_U = (const float*)d_in[6];
  const float* k_V = (const float*)d_in[7];
  const float* k_bias = (const float*)d_in[8];
  const float* v_U = (const float*)d_in[9];
  const float* v_V = (const float*)d_in[10];
  const float* v_bias = (const float*)d_in[11];
  const float* out_U = (const float*)d_in[12];
  const float* out_V = (const float*)d_in[13];
  const float* out_bias = (const float*)d_in[14];
  const float* ln2_w = (const float*)d_in[15];
  const float* ln2_b = (const float*)d_in[16];
  const float* fc1_U = (const float*)d_in[17];
  const float* fc1_V = (const float*)d_in[18];
  const float* fc1_bias = (const float*)d_in[19];
  const float* fc2_U = (const float*)d_in[20];
  const float* fc2_V = (const float*)d_in[21];
  const float* fc2_bias = (const float*)d_in[22];
  float* out = (float*)d_out;
  float* ws = (float*)d_ws;
  unsigned short* wsu = (unsigned short*)d_ws;

  // ---- bf16 weight arena (ushort offsets) ----
  unsigned short* wQKV = wsu;               // [1536,1024] (q_V|k_V|v_V)
  unsigned short* wKV = wsu + 524288;
  unsigned short* wVV = wsu + 1048576;
  unsigned short* wOUTV = wsu + 1572864;    // [512,1024]
  unsigned short* wOUTU = wsu + 2097152;    // [1024,512]
  unsigned short* wFC1V = wsu + 2621440;    // [512,1024]
  unsigned short* wFC1U = wsu + 3145728;    // [4096,512]
  unsigned short* wFC2V = wsu + 5242880;    // [512,4096]
  unsigned short* wFC2U = wsu + 7340032;    // [1024,512]

  // ---- activation arena (float offsets) ----
  float* h1 = ws + 4194304;                          // [4096,1024] fp32
  unsigned short* attn_out = (unsigned short*)(ws + 6291456);  // [4096,1024] bf16
  unsigned short* normed = (unsigned short*)(ws + 8388608);    // [4096,1024] bf16
  float* rb = ws + 10485760;                         // [4096,1536] fp32 (QKV t)
  unsigned short* rbB = (unsigned short*)(ws + 10485760);      // [4096,512] bf16
  unsigned short* ff = (unsigned short*)(ws + 11534336);       // [4096,4096] bf16
  unsigned short* qbuf = (unsigned short*)(ws + 16777216);
  unsigned short* kbuf = (unsigned short*)(ws + 18874368);
  unsigned short* rbG = (unsigned short*)(ws + 19922944);      // [4096,512] bf16
  unsigned short* vtbuf = (unsigned short*)(ws + 20971520);

  const int M = Bc * Sc;  // 4096
  dim3 blk(256);

  // ---- weight conversion ----
  convert3<<<1536, blk, 0, stream>>>(q_V, 524288, k_V, 524288, v_V, 524288, wQKV, wKV, wVV);
  convert3<<<1536, blk, 0, stream>>>(out_V, 524288, out_U, 524288, fc1_V, 524288, wOUTV, wOUTU, wFC1V);
  convert3<<<4608, blk, 0, stream>>>(fc1_U, 2097152, fc2_V, 2097152, fc2_U, 524288, wFC1U, wFC2V, wFC2U);

  // ---- LN1 ----
  ln_bf16<<<M, blk, 0, stream>>>(hidden, ln1_w, ln1_b, normed);

  // ---- fused QKV rank contraction: rb[4096,1536] = normed * [qV|kV|vV]^T ----
  gemm_bf16<64, 64><<<dim3(24, 64), blk, 0, stream>>>(normed, wQKV, rb, nullptr, nullptr, nullptr,
                                                      M, 1536, Dc, 0);
  expand_head_qk_frag<<<2048, blk, 0, stream>>>(rb, 1536, q_U, q_bias, qbuf);
  expand_head_qk_frag<<<2048, blk, 0, stream>>>(rb + 512, 1536, k_U, k_bias, kbuf);
  expand_head_vT_frag<<<2048, blk, 0, stream>>>(rb + 1024, 1536, v_U, v_bias, vtbuf);

  // ---- causal attention -> attn_out (bf16) ----
  attn_mfma<<<2048, blk, 0, stream>>>(qbuf, kbuf, vtbuf, attn_out);

  // ---- output projection + residual -> h1 (fp32) ----
  gemm_bf16<64, 64><<<dim3(8, 64), blk, 0, stream>>>(attn_out, wOUTV, nullptr, rbB, nullptr, nullptr,
                                                     M, 512, Dc, 0);
  gemm_bf16<64, 64><<<dim3(16, 64), blk, 0, stream>>>(rbB, wOUTU, h1, nullptr, out_bias, hidden,
                                                      M, Dc, 512, 0);

  // ---- LN2 + FF ----
  ln_bf16<<<M, blk, 0, stream>>>(h1, ln2_w, ln2_b, normed);
  gemm_bf16<64, 64><<<dim3(8, 64), blk, 0, stream>>>(normed, wFC1V, nullptr, rbB, nullptr, nullptr,
                                                     M, 512, Dc, 0);
  gemm_bf16<128, 128><<<dim3(32, 32), blk, 0, stream>>>(rbB, wFC1U, nullptr, ff, fc1_bias, nullptr,
                                                        M, DFFc, 512, 1);
  gemm_bf16<64, 64><<<dim3(8, 64), blk, 0, stream>>>(ff, wFC2V, nullptr, rbG, nullptr, nullptr,
                                                     M, 512, DFFc, 0);
  gemm_bf16<64, 64><<<dim3(16, 64), blk, 0, stream>>>(rbG, wFC2U, out, nullptr, fc2_bias, h1,
                                                      M, Dc, 512, 0);
}